// Round 1
// baseline (3957.499 us; speedup 1.0000x reference)
//
#include <hip/hip_runtime.h>

#define N_NODES 200000
#define N_EDGES 6400000
#define N_GRAPHS 512

// ---------------- workspace layout (floats) ----------------
// Zero-init region (one memset):
//   agg1   : ws + 0            size 3*N
//   agg2   : ws + 3N           size 16*N
//   agg3   : ws + 19N          size 8*N
//   pooled : ws + 27N          size 512*8   (uint bits; 0 == 0.0f, valid since relu>=0)
// Written-before-read region:
//   t2     : ws + 27N + 4096   size 16*N
//   r2     : +16N
//   t3     : +8N
//   r3     : +8N
// total = 75*N + 4096 floats ~= 60 MB

// ---- L1 scatter: agg1[dst] += x[src], 3 floats/edge ----
__global__ __launch_bounds__(256) void scatter3_kernel(
    const int* __restrict__ src, const int* __restrict__ dst,
    const float* __restrict__ x, float* __restrict__ agg) {
  int e = blockIdx.x * blockDim.x + threadIdx.x;
  if (e >= N_EDGES) return;
  int s = src[e], d = dst[e];
  float v0 = x[3 * s + 0], v1 = x[3 * s + 1], v2 = x[3 * s + 2];
  atomicAdd(&agg[3 * d + 0], v0);
  atomicAdd(&agg[3 * d + 1], v1);
  atomicAdd(&agg[3 * d + 2], v2);
}

// ---- generic scatter: F floats per node, F/4 threads per edge, float4 gather ----
template <int F>
__global__ __launch_bounds__(256) void scatterF_kernel(
    const int* __restrict__ src, const int* __restrict__ dst,
    const float* __restrict__ val, float* __restrict__ agg) {
  const int TPE = F / 4;
  int tid = blockIdx.x * blockDim.x + threadIdx.x;
  int e = tid / TPE;
  if (e >= N_EDGES) return;
  int part = tid - e * TPE;
  int s = src[e], d = dst[e];
  const float4 v = *(const float4*)&val[(size_t)s * F + part * 4];
  float* a = &agg[(size_t)d * F + part * 4];
  atomicAdd(a + 0, v.x);
  atomicAdd(a + 1, v.y);
  atomicAdd(a + 2, v.z);
  atomicAdd(a + 3, v.w);
}

// ---- node kernel A: h1 = relu(W1_rel@agg1 + b1 + W1_root@x); t2 = W2_rel@h1; r2 = W2_root@h1 ----
__global__ __launch_bounds__(256) void nodeA_kernel(
    const float* __restrict__ x, const float* __restrict__ agg1,
    const float* __restrict__ W1_rel, const float* __restrict__ b1,
    const float* __restrict__ W1_root,
    const float* __restrict__ W2_rel, const float* __restrict__ W2_root,
    float* __restrict__ t2, float* __restrict__ r2) {
  __shared__ float sW1rel[96], sb1[32], sW1root[96], sW2rel[512], sW2root[512];
  for (int i = threadIdx.x; i < 96; i += blockDim.x) {
    sW1rel[i] = W1_rel[i];
    sW1root[i] = W1_root[i];
  }
  for (int i = threadIdx.x; i < 32; i += blockDim.x) sb1[i] = b1[i];
  for (int i = threadIdx.x; i < 512; i += blockDim.x) {
    sW2rel[i] = W2_rel[i];
    sW2root[i] = W2_root[i];
  }
  __syncthreads();
  int n = blockIdx.x * blockDim.x + threadIdx.x;
  if (n >= N_NODES) return;
  float a0 = agg1[3 * n + 0], a1 = agg1[3 * n + 1], a2 = agg1[3 * n + 2];
  float x0 = x[3 * n + 0], x1 = x[3 * n + 1], x2 = x[3 * n + 2];
  float h[32];
#pragma unroll
  for (int k = 0; k < 32; k++) {
    float v = sW1rel[3 * k + 0] * a0 + sW1rel[3 * k + 1] * a1 + sW1rel[3 * k + 2] * a2 +
              sW1root[3 * k + 0] * x0 + sW1root[3 * k + 1] * x1 + sW1root[3 * k + 2] * x2 +
              sb1[k];
    h[k] = fmaxf(v, 0.0f);
  }
  size_t base = (size_t)n * 16;
#pragma unroll
  for (int j = 0; j < 16; j++) {
    float acc = 0.0f, accr = 0.0f;
#pragma unroll
    for (int k = 0; k < 32; k++) {
      acc += sW2rel[32 * j + k] * h[k];
      accr += sW2root[32 * j + k] * h[k];
    }
    t2[base + j] = acc;
    r2[base + j] = accr;
  }
}

// ---- node kernel B: h2 = relu(agg2 + b2 + r2); t3 = W3_rel@h2; r3 = W3_root@h2 ----
__global__ __launch_bounds__(256) void nodeB_kernel(
    const float* __restrict__ agg2, const float* __restrict__ r2,
    const float* __restrict__ b2,
    const float* __restrict__ W3_rel, const float* __restrict__ W3_root,
    float* __restrict__ t3, float* __restrict__ r3) {
  __shared__ float sW3rel[128], sW3root[128], sb2[16];
  for (int i = threadIdx.x; i < 128; i += blockDim.x) {
    sW3rel[i] = W3_rel[i];
    sW3root[i] = W3_root[i];
  }
  for (int i = threadIdx.x; i < 16; i += blockDim.x) sb2[i] = b2[i];
  __syncthreads();
  int n = blockIdx.x * blockDim.x + threadIdx.x;
  if (n >= N_NODES) return;
  size_t base = (size_t)n * 16;
  float h[16];
#pragma unroll
  for (int j = 0; j < 16; j++) {
    h[j] = fmaxf(agg2[base + j] + sb2[j] + r2[base + j], 0.0f);
  }
  size_t base8 = (size_t)n * 8;
#pragma unroll
  for (int j = 0; j < 8; j++) {
    float acc = 0.0f, accr = 0.0f;
#pragma unroll
    for (int k = 0; k < 16; k++) {
      acc += sW3rel[16 * j + k] * h[k];
      accr += sW3root[16 * j + k] * h[k];
    }
    t3[base8 + j] = acc;
    r3[base8 + j] = accr;
  }
}

// ---- node kernel C: h3 = relu(agg3 + b3 + r3); pooled[batch[n]] = max(...) ----
__global__ __launch_bounds__(256) void nodeC_kernel(
    const float* __restrict__ agg3, const float* __restrict__ r3,
    const float* __restrict__ b3, const int* __restrict__ batch,
    unsigned int* __restrict__ pooled) {
  int n = blockIdx.x * blockDim.x + threadIdx.x;
  if (n >= N_NODES) return;
  int g = batch[n];
  size_t base = (size_t)n * 8;
#pragma unroll
  for (int f = 0; f < 8; f++) {
    float h = fmaxf(agg3[base + f] + b3[f] + r3[base + f], 0.0f);
    // relu >= 0, so IEEE float ordering == unsigned int ordering; pooled init 0 == 0.0f
    atomicMax(&pooled[8 * g + f], __float_as_uint(h));
  }
}

// ---- final: out[g] = pooled[g] . W_lin + b_lin ----
__global__ __launch_bounds__(256) void final_kernel(
    const unsigned int* __restrict__ pooled, const float* __restrict__ W_lin,
    const float* __restrict__ b_lin, float* __restrict__ out) {
  int g = blockIdx.x * blockDim.x + threadIdx.x;
  if (g >= N_GRAPHS) return;
  float acc = b_lin[0];
#pragma unroll
  for (int f = 0; f < 8; f++) acc += __uint_as_float(pooled[8 * g + f]) * W_lin[f];
  out[g] = acc;
}

extern "C" void kernel_launch(void* const* d_in, const int* in_sizes, int n_in,
                              void* d_out, int out_size, void* d_ws, size_t ws_size,
                              hipStream_t stream) {
  const float* x = (const float*)d_in[0];
  const int* ei = (const int*)d_in[1];
  const int* src = ei;
  const int* dst = ei + N_EDGES;
  const int* batch = (const int*)d_in[2];
  const float* W1_rel = (const float*)d_in[3];
  const float* b1 = (const float*)d_in[4];
  const float* W1_root = (const float*)d_in[5];
  const float* W2_rel = (const float*)d_in[6];
  const float* b2 = (const float*)d_in[7];
  const float* W2_root = (const float*)d_in[8];
  const float* W3_rel = (const float*)d_in[9];
  const float* b3 = (const float*)d_in[10];
  const float* W3_root = (const float*)d_in[11];
  const float* W_lin = (const float*)d_in[12];
  const float* b_lin = (const float*)d_in[13];
  float* out = (float*)d_out;

  const size_t N = N_NODES;
  float* ws = (float*)d_ws;
  float* agg1 = ws;                        // 3N
  float* agg2 = ws + 3 * N;                // 16N
  float* agg3 = ws + 19 * N;               // 8N
  unsigned int* pooled = (unsigned int*)(ws + 27 * N);  // 4096
  float* t2 = ws + 27 * N + 4096;          // 16N
  float* r2 = t2 + 16 * N;                 // 16N
  float* t3 = r2 + 16 * N;                 // 8N
  float* r3 = t3 + 8 * N;                  // 8N

  // single memset over the contiguous zero-init region: agg1|agg2|agg3|pooled
  hipMemsetAsync(ws, 0, (27 * N + 4096) * sizeof(float), stream);

  const int B = 256;
  // layer 1
  scatter3_kernel<<<(N_EDGES + B - 1) / B, B, 0, stream>>>(src, dst, x, agg1);
  nodeA_kernel<<<(N_NODES + B - 1) / B, B, 0, stream>>>(x, agg1, W1_rel, b1, W1_root,
                                                        W2_rel, W2_root, t2, r2);
  // layer 2 (aggregate in 16-dim post-transform space)
  {
    int threads = N_EDGES * 4;  // 4 threads/edge
    scatterF_kernel<16><<<(threads + B - 1) / B, B, 0, stream>>>(src, dst, t2, agg2);
  }
  nodeB_kernel<<<(N_NODES + B - 1) / B, B, 0, stream>>>(agg2, r2, b2, W3_rel, W3_root, t3, r3);
  // layer 3 (aggregate in 8-dim post-transform space)
  {
    int threads = N_EDGES * 2;  // 2 threads/edge
    scatterF_kernel<8><<<(threads + B - 1) / B, B, 0, stream>>>(src, dst, t3, agg3);
  }
  nodeC_kernel<<<(N_NODES + B - 1) / B, B, 0, stream>>>(agg3, r3, b3, batch, pooled);
  final_kernel<<<(N_GRAPHS + B - 1) / B, B, 0, stream>>>(pooled, W_lin, b_lin, out);
}

// Round 2
// 1800.918 us; speedup vs baseline: 2.1975x; 2.1975x over previous
//
#include <hip/hip_runtime.h>

#define N_NODES 200000
#define N_EDGES 6400000
#define N_GRAPHS 512

#define NB 782        // dst buckets of 256 nodes: ceil(200000/256)
#define BSH 8
#define BMASK 255
#define NCH 784       // edge chunks for the counting sort
#define CHUNK 8192    // edges per chunk (784*8192 >= 6.4M)

__device__ __forceinline__ unsigned short f2bf(float v) {
  unsigned u = __float_as_uint(v);
  u += 0x7FFFu + ((u >> 16) & 1u);  // round-to-nearest-even
  return (unsigned short)(u >> 16);
}
__device__ __forceinline__ float bf2f(unsigned b) {
  return __uint_as_float(b << 16);
}

// ---------- partition phase: counting sort of edges by dst>>8 ----------

__global__ __launch_bounds__(256) void count_kernel(const int* __restrict__ dst,
                                                    unsigned* __restrict__ H) {
  __shared__ unsigned hist[NB];
  for (int i = threadIdx.x; i < NB; i += 256) hist[i] = 0;
  __syncthreads();
  int c = blockIdx.x;
  long e0 = (long)c * CHUNK;
  long rem = (long)N_EDGES - e0;
  int n = rem > CHUNK ? CHUNK : (rem > 0 ? (int)rem : 0);
  for (int i = threadIdx.x; i < n; i += 256) {
    int d = dst[e0 + i];
    atomicAdd(&hist[d >> BSH], 1u);
  }
  __syncthreads();
  for (int i = threadIdx.x; i < NB; i += 256) H[(size_t)i * NCH + c] = hist[i];
}

// per-bin exclusive scan over chunks; H[b][c] becomes within-bin offset of chunk c
__global__ __launch_bounds__(256) void scan_bins_kernel(unsigned* __restrict__ H,
                                                        unsigned* __restrict__ bucketTotal) {
  int b = blockIdx.x * 256 + threadIdx.x;
  if (b >= NB) return;
  unsigned run = 0;
  size_t base = (size_t)b * NCH;
  for (int c = 0; c < NCH; c++) {
    unsigned t = H[base + c];
    H[base + c] = run;
    run += t;
  }
  bucketTotal[b] = run;
}

// exclusive scan of bucketTotal -> bucketStart (one block, Hillis-Steele)
__global__ __launch_bounds__(1024) void scan_total_kernel(const unsigned* __restrict__ bucketTotal,
                                                          unsigned* __restrict__ bucketStart) {
  __shared__ unsigned s[1024];
  int t = threadIdx.x;
  unsigned v = (t < NB) ? bucketTotal[t] : 0u;
  s[t] = v;
  __syncthreads();
  for (int off = 1; off < 1024; off <<= 1) {
    unsigned add = (t >= off) ? s[t - off] : 0u;
    __syncthreads();
    s[t] += add;
    __syncthreads();
  }
  if (t < NB) bucketStart[t] = s[t] - v;
}

__global__ __launch_bounds__(256) void scatter_edges_kernel(
    const int* __restrict__ src, const int* __restrict__ dst,
    const unsigned* __restrict__ H, const unsigned* __restrict__ bucketStart,
    unsigned* __restrict__ packed) {
  __shared__ unsigned cur[NB];
  int c = blockIdx.x;
  for (int i = threadIdx.x; i < NB; i += 256)
    cur[i] = bucketStart[i] + H[(size_t)i * NCH + c];
  __syncthreads();
  long e0 = (long)c * CHUNK;
  long rem = (long)N_EDGES - e0;
  int n = rem > CHUNK ? CHUNK : (rem > 0 ? (int)rem : 0);
  for (int i = threadIdx.x; i < n; i += 256) {
    int s = src[e0 + i], d = dst[e0 + i];
    unsigned pos = atomicAdd(&cur[d >> BSH], 1u);
    packed[pos] = ((unsigned)s << BSH) | (unsigned)(d & BMASK);
  }
}

// ---------- layer 1: LDS-accumulate x (3f) per bucket, fused node transform ----------
// epilogue: h1 = relu(W1_rel@agg + b1 + W1_root@x); t2 = W2_rel@h1; r2 = W2_root@h1

__global__ __launch_bounds__(512) void layer1_kernel(
    const unsigned* __restrict__ packed, const unsigned* __restrict__ bucketStart,
    const unsigned* __restrict__ bucketTotal, const float* __restrict__ x,
    const float* __restrict__ W1_rel, const float* __restrict__ b1,
    const float* __restrict__ W1_root,
    const float* __restrict__ W2_rel, const float* __restrict__ W2_root,
    float* __restrict__ t2, float* __restrict__ r2) {
  __shared__ float agg[256 * 5];  // stride 5 (coprime 32) to spread ds_add banks
  __shared__ float sW1rel[96], sW1root[96], sb1[32], sW2rel[512], sW2root[512];
  for (int i = threadIdx.x; i < 256 * 5; i += 512) agg[i] = 0.f;
  for (int i = threadIdx.x; i < 96; i += 512) { sW1rel[i] = W1_rel[i]; sW1root[i] = W1_root[i]; }
  for (int i = threadIdx.x; i < 32; i += 512) sb1[i] = b1[i];
  for (int i = threadIdx.x; i < 512; i += 512) { sW2rel[i] = W2_rel[i]; sW2root[i] = W2_root[i]; }
  __syncthreads();
  int b = blockIdx.x;
  unsigned e0 = bucketStart[b], n = bucketTotal[b];
  for (unsigned i = threadIdx.x; i < n; i += 512) {
    unsigned p = packed[e0 + i];
    int s = (int)(p >> BSH), dl = (int)(p & BMASK);
    float v0 = x[3 * s], v1 = x[3 * s + 1], v2 = x[3 * s + 2];
    atomicAdd(&agg[dl * 5 + 0], v0);
    atomicAdd(&agg[dl * 5 + 1], v1);
    atomicAdd(&agg[dl * 5 + 2], v2);
  }
  __syncthreads();
  int t = threadIdx.x;
  int node = b * 256 + t;
  if (t < 256 && node < N_NODES) {
    float a0 = agg[t * 5], a1 = agg[t * 5 + 1], a2 = agg[t * 5 + 2];
    float x0 = x[3 * node], x1 = x[3 * node + 1], x2 = x[3 * node + 2];
    float h[32];
#pragma unroll
    for (int k = 0; k < 32; k++) {
      float v = sW1rel[3 * k] * a0 + sW1rel[3 * k + 1] * a1 + sW1rel[3 * k + 2] * a2 +
                sW1root[3 * k] * x0 + sW1root[3 * k + 1] * x1 + sW1root[3 * k + 2] * x2 + sb1[k];
      h[k] = fmaxf(v, 0.f);
    }
    size_t base = (size_t)node * 16;
#pragma unroll
    for (int j = 0; j < 16; j++) {
      float acc = 0.f, accr = 0.f;
#pragma unroll
      for (int k = 0; k < 32; k++) {
        acc += sW2rel[32 * j + k] * h[k];
        accr += sW2root[32 * j + k] * h[k];
      }
      t2[base + j] = acc;
      r2[base + j] = accr;
    }
  }
}

// ---------- layer 2: LDS-accumulate t2 (16f, 4 thr/edge float4), fused transform ----------
// epilogue: h2 = relu(agg + b2 + r2); t3 = W3_rel@h2; r3 = W3_root@h2 -> tr3 (bf16)

__global__ __launch_bounds__(512) void layer2_kernel(
    const unsigned* __restrict__ packed, const unsigned* __restrict__ bucketStart,
    const unsigned* __restrict__ bucketTotal,
    const float* __restrict__ t2, const float* __restrict__ r2,
    const float* __restrict__ b2,
    const float* __restrict__ W3_rel, const float* __restrict__ W3_root,
    unsigned* __restrict__ tr3) {
  __shared__ float agg[256 * 17];  // stride 17 (coprime 32)
  __shared__ float sW3rel[128], sW3root[128], sb2[16];
  for (int i = threadIdx.x; i < 256 * 17; i += 512) agg[i] = 0.f;
  for (int i = threadIdx.x; i < 128; i += 512) { sW3rel[i] = W3_rel[i]; sW3root[i] = W3_root[i]; }
  if (threadIdx.x < 16) sb2[threadIdx.x] = b2[threadIdx.x];
  __syncthreads();
  int b = blockIdx.x;
  unsigned e0 = bucketStart[b], n4 = bucketTotal[b] * 4;
  for (unsigned j = threadIdx.x; j < n4; j += 512) {
    unsigned p = packed[e0 + (j >> 2)];
    int part = (int)(j & 3);
    int s = (int)(p >> BSH), dl = (int)(p & BMASK);
    const float4 v = *(const float4*)&t2[(size_t)s * 16 + part * 4];
    int a = dl * 17 + part * 4;
    atomicAdd(&agg[a + 0], v.x);
    atomicAdd(&agg[a + 1], v.y);
    atomicAdd(&agg[a + 2], v.z);
    atomicAdd(&agg[a + 3], v.w);
  }
  __syncthreads();
  int t = threadIdx.x;
  int node = b * 256 + t;
  if (t < 256 && node < N_NODES) {
    size_t base = (size_t)node * 16;
    float h[16];
#pragma unroll
    for (int j = 0; j < 16; j++) h[j] = fmaxf(agg[t * 17 + j] + sb2[j] + r2[base + j], 0.f);
    float t3v[8], r3v[8];
#pragma unroll
    for (int j = 0; j < 8; j++) {
      float a3 = 0.f, ar = 0.f;
#pragma unroll
      for (int k = 0; k < 16; k++) {
        a3 += sW3rel[16 * j + k] * h[k];
        ar += sW3root[16 * j + k] * h[k];
      }
      t3v[j] = a3;
      r3v[j] = ar;
    }
    size_t ob = (size_t)node * 8;
#pragma unroll
    for (int j = 0; j < 4; j++) {
      tr3[ob + j] = (unsigned)f2bf(t3v[2 * j]) | ((unsigned)f2bf(t3v[2 * j + 1]) << 16);
      tr3[ob + 4 + j] = (unsigned)f2bf(r3v[2 * j]) | ((unsigned)f2bf(r3v[2 * j + 1]) << 16);
    }
  }
}

// ---------- layer 3: LDS-accumulate t3 (8 bf16 per edge), fused relu + pooled max ----------

__global__ __launch_bounds__(512) void layer3_kernel(
    const unsigned* __restrict__ packed, const unsigned* __restrict__ bucketStart,
    const unsigned* __restrict__ bucketTotal,
    const unsigned* __restrict__ tr3, const float* __restrict__ b3,
    const int* __restrict__ batch, unsigned* __restrict__ pooled) {
  __shared__ float agg[256 * 9];  // stride 9 (coprime 32)
  __shared__ float sb3[8];
  for (int i = threadIdx.x; i < 256 * 9; i += 512) agg[i] = 0.f;
  if (threadIdx.x < 8) sb3[threadIdx.x] = b3[threadIdx.x];
  __syncthreads();
  int b = blockIdx.x;
  unsigned e0 = bucketStart[b], n = bucketTotal[b];
  for (unsigned i = threadIdx.x; i < n; i += 512) {
    unsigned p = packed[e0 + i];
    int s = (int)(p >> BSH), dl = (int)(p & BMASK);
    const uint4 raw = *(const uint4*)&tr3[(size_t)s * 8];  // t3[0..7] bf16
    int a = dl * 9;
    atomicAdd(&agg[a + 0], bf2f(raw.x & 0xffffu));
    atomicAdd(&agg[a + 1], bf2f(raw.x >> 16));
    atomicAdd(&agg[a + 2], bf2f(raw.y & 0xffffu));
    atomicAdd(&agg[a + 3], bf2f(raw.y >> 16));
    atomicAdd(&agg[a + 4], bf2f(raw.z & 0xffffu));
    atomicAdd(&agg[a + 5], bf2f(raw.z >> 16));
    atomicAdd(&agg[a + 6], bf2f(raw.w & 0xffffu));
    atomicAdd(&agg[a + 7], bf2f(raw.w >> 16));
  }
  __syncthreads();
  int t = threadIdx.x;
  int node = b * 256 + t;
  if (t < 256 && node < N_NODES) {
    int g = batch[node];
    const uint4 rr = *(const uint4*)&tr3[(size_t)node * 8 + 4];  // r3[0..7] bf16
    float r[8] = {bf2f(rr.x & 0xffffu), bf2f(rr.x >> 16), bf2f(rr.y & 0xffffu), bf2f(rr.y >> 16),
                  bf2f(rr.z & 0xffffu), bf2f(rr.z >> 16), bf2f(rr.w & 0xffffu), bf2f(rr.w >> 16)};
#pragma unroll
    for (int f = 0; f < 8; f++) {
      float h = fmaxf(agg[t * 9 + f] + sb3[f] + r[f], 0.f);
      atomicMax(&pooled[8 * g + f], __float_as_uint(h));  // relu>=0: uint order == float order
    }
  }
}

__global__ __launch_bounds__(256) void final_kernel(
    const unsigned* __restrict__ pooled, const float* __restrict__ W_lin,
    const float* __restrict__ b_lin, float* __restrict__ out) {
  int g = blockIdx.x * blockDim.x + threadIdx.x;
  if (g >= N_GRAPHS) return;
  float acc = b_lin[0];
#pragma unroll
  for (int f = 0; f < 8; f++) acc += __uint_as_float(pooled[8 * g + f]) * W_lin[f];
  out[g] = acc;
}

extern "C" void kernel_launch(void* const* d_in, const int* in_sizes, int n_in,
                              void* d_out, int out_size, void* d_ws, size_t ws_size,
                              hipStream_t stream) {
  const float* x = (const float*)d_in[0];
  const int* ei = (const int*)d_in[1];
  const int* src = ei;
  const int* dst = ei + N_EDGES;
  const int* batch = (const int*)d_in[2];
  const float* W1_rel = (const float*)d_in[3];
  const float* b1 = (const float*)d_in[4];
  const float* W1_root = (const float*)d_in[5];
  const float* W2_rel = (const float*)d_in[6];
  const float* b2 = (const float*)d_in[7];
  const float* W2_root = (const float*)d_in[8];
  const float* W3_rel = (const float*)d_in[9];
  const float* b3 = (const float*)d_in[10];
  const float* W3_root = (const float*)d_in[11];
  const float* W_lin = (const float*)d_in[12];
  const float* b_lin = (const float*)d_in[13];
  float* out = (float*)d_out;

  // ---- workspace layout (bytes) ----
  char* ws = (char*)d_ws;
  unsigned* packed = (unsigned*)(ws + 0);              // 25,600,000
  float* t2 = (float*)(ws + 25600000);                 // 12,800,000
  unsigned* H = (unsigned*)(ws + 25600000);            // alias: 2,452,352 used pre-layer1
  float* r2 = (float*)(ws + 38400000);                 // 12,800,000
  unsigned* tr3 = (unsigned*)(ws + 51200000);          // 6,400,000
  unsigned* pooled = (unsigned*)(ws + 57600000);       // 16,384
  unsigned* bucketTotal = (unsigned*)(ws + 57616384);  // 3,136
  unsigned* bucketStart = (unsigned*)(ws + 57619520);  // 3,136

  hipMemsetAsync(pooled, 0, N_GRAPHS * 8 * sizeof(unsigned), stream);

  // partition (counting sort by dst bucket)
  count_kernel<<<NCH, 256, 0, stream>>>(dst, H);
  scan_bins_kernel<<<(NB + 255) / 256, 256, 0, stream>>>(H, bucketTotal);
  scan_total_kernel<<<1, 1024, 0, stream>>>(bucketTotal, bucketStart);
  scatter_edges_kernel<<<NCH, 256, 0, stream>>>(src, dst, H, bucketStart, packed);

  // layers (LDS accumulation per bucket, fused node transforms)
  layer1_kernel<<<NB, 512, 0, stream>>>(packed, bucketStart, bucketTotal, x,
                                        W1_rel, b1, W1_root, W2_rel, W2_root, t2, r2);
  layer2_kernel<<<NB, 512, 0, stream>>>(packed, bucketStart, bucketTotal,
                                        t2, r2, b2, W3_rel, W3_root, tr3);
  layer3_kernel<<<NB, 512, 0, stream>>>(packed, bucketStart, bucketTotal,
                                        tr3, b3, batch, pooled);
  final_kernel<<<(N_GRAPHS + 255) / 256, 256, 0, stream>>>(pooled, W_lin, b_lin, out);
}

// Round 3
// 1680.585 us; speedup vs baseline: 2.3548x; 1.0716x over previous
//
#include <hip/hip_runtime.h>
#include <hip/hip_fp16.h>

#define N_NODES 200000
#define N_EDGES 6400000
#define N_GRAPHS 512

#define NB 782        // dst buckets of 256 nodes: ceil(200000/256)
#define BSH 8
#define BMASK 255
#define NCH 782       // edge chunks: 782*8192 = 6,406,144 >= 6.4M
#define CHUNK 8192

// ---------- partition phase: counting sort of edges by dst>>8 ----------
// H layout is TRANSPOSED: H[c*NB + b]  (coalesced in both count and scan)

__global__ __launch_bounds__(256) void count_kernel(const int* __restrict__ dst,
                                                    unsigned* __restrict__ H) {
  __shared__ unsigned hist[NB];
  for (int i = threadIdx.x; i < NB; i += 256) hist[i] = 0;
  __syncthreads();
  int c = blockIdx.x;
  long e0 = (long)c * CHUNK;
  long rem = (long)N_EDGES - e0;
  int n = rem > CHUNK ? CHUNK : (rem > 0 ? (int)rem : 0);
  for (int i = threadIdx.x; i < n; i += 256) {
    int d = dst[e0 + i];
    atomicAdd(&hist[d >> BSH], 1u);
  }
  __syncthreads();
  for (int i = threadIdx.x; i < NB; i += 256) H[(size_t)c * NB + i] = hist[i];
}

// per-bin exclusive scan over chunks; H[c][b] becomes within-bin offset of chunk c
__global__ __launch_bounds__(256) void scan_bins_kernel(unsigned* __restrict__ H,
                                                        unsigned* __restrict__ bucketTotal) {
  int b = blockIdx.x * 256 + threadIdx.x;
  if (b >= NB) return;
  unsigned run = 0;
  for (int c = 0; c < NCH; c++) {
    unsigned t = H[(size_t)c * NB + b];  // coalesced across threads
    H[(size_t)c * NB + b] = run;
    run += t;
  }
  bucketTotal[b] = run;
}

// exclusive scan of bucketTotal -> bucketStart (one block, Hillis-Steele)
__global__ __launch_bounds__(1024) void scan_total_kernel(const unsigned* __restrict__ bucketTotal,
                                                          unsigned* __restrict__ bucketStart) {
  __shared__ unsigned s[1024];
  int t = threadIdx.x;
  unsigned v = (t < NB) ? bucketTotal[t] : 0u;
  s[t] = v;
  __syncthreads();
  for (int off = 1; off < 1024; off <<= 1) {
    unsigned add = (t >= off) ? s[t - off] : 0u;
    __syncthreads();
    s[t] += add;
    __syncthreads();
  }
  if (t < NB) bucketStart[t] = s[t] - v;
}

// chunk-local LDS counting sort, then coalesced-run writes of packed
__global__ __launch_bounds__(256) void scatter_sorted_kernel(
    const int* __restrict__ src, const int* __restrict__ dst,
    const unsigned* __restrict__ H, const unsigned* __restrict__ bucketStart,
    unsigned* __restrict__ packed) {
  __shared__ unsigned ssort[CHUNK];          // 32 KB sorted payloads
  __shared__ unsigned short sbort[CHUNK];    // 16 KB bucket of each sorted slot
  __shared__ unsigned hist[1024];            // local exclusive offsets (padded)
  __shared__ unsigned cur[1024];
  __shared__ unsigned partial[256];
  int t = threadIdx.x;
  int c = blockIdx.x;
  long e0 = (long)c * CHUNK;
  long rem = (long)N_EDGES - e0;
  int n = rem > CHUNK ? CHUNK : (rem > 0 ? (int)rem : 0);
  for (int i = t; i < 1024; i += 256) hist[i] = 0;
  __syncthreads();
  // pass 1: count
  for (int i = t; i < n; i += 256) {
    int d = dst[e0 + i];
    atomicAdd(&hist[d >> BSH], 1u);
  }
  __syncthreads();
  // block exclusive scan of hist[0..1023]
  unsigned a0 = hist[4 * t], a1 = hist[4 * t + 1], a2 = hist[4 * t + 2], a3 = hist[4 * t + 3];
  unsigned sum = a0 + a1 + a2 + a3;
  partial[t] = sum;
  __syncthreads();
  for (int off = 1; off < 256; off <<= 1) {
    unsigned add = (t >= off) ? partial[t - off] : 0u;
    __syncthreads();
    partial[t] += add;
    __syncthreads();
  }
  unsigned excl = partial[t] - sum;
  hist[4 * t] = excl;
  hist[4 * t + 1] = excl + a0;
  hist[4 * t + 2] = excl + a0 + a1;
  hist[4 * t + 3] = excl + a0 + a1 + a2;
  cur[4 * t] = excl;
  cur[4 * t + 1] = excl + a0;
  cur[4 * t + 2] = excl + a0 + a1;
  cur[4 * t + 3] = excl + a0 + a1 + a2;
  __syncthreads();
  // pass 2: place into LDS in bucket-sorted order
  for (int i = t; i < n; i += 256) {
    int d = dst[e0 + i], s = src[e0 + i];
    int b = d >> BSH;
    unsigned r = atomicAdd(&cur[b], 1u);
    ssort[r] = ((unsigned)s << BSH) | (unsigned)(d & BMASK);
    sbort[r] = (unsigned short)b;
  }
  __syncthreads();
  // base[b] = bucketStart[b] + H[c][b] - localExcl[b]  (reuse cur as base)
  for (int b = t; b < NB; b += 256)
    cur[b] = bucketStart[b] + H[(size_t)c * NB + b] - hist[b];
  __syncthreads();
  // pass 3: writes in sorted order -> coalesced runs per bucket
  for (int j = t; j < n; j += 256) {
    packed[cur[sbort[j]] + j] = ssort[j];
  }
}

// ---------- xpad: x padded to float4 for single-line gathers ----------
__global__ __launch_bounds__(256) void xpad_kernel(const float* __restrict__ x,
                                                   float4* __restrict__ xp) {
  int n = blockIdx.x * 256 + threadIdx.x;
  if (n >= N_NODES) return;
  xp[n] = make_float4(x[3 * n], x[3 * n + 1], x[3 * n + 2], 0.f);
}

// ---------- layer 1 ----------
__global__ __launch_bounds__(512) void layer1_kernel(
    const unsigned* __restrict__ packed, const unsigned* __restrict__ bucketStart,
    const unsigned* __restrict__ bucketTotal, const float4* __restrict__ xp,
    const float* __restrict__ W1_rel, const float* __restrict__ b1,
    const float* __restrict__ W1_root,
    const float* __restrict__ W2_rel, const float* __restrict__ W2_root,
    unsigned* __restrict__ t2h, float* __restrict__ r2) {
  __shared__ float agg[256 * 5];
  __shared__ float sW1rel[96], sW1root[96], sb1[32], sW2rel[512], sW2root[512];
  for (int i = threadIdx.x; i < 256 * 5; i += 512) agg[i] = 0.f;
  for (int i = threadIdx.x; i < 96; i += 512) { sW1rel[i] = W1_rel[i]; sW1root[i] = W1_root[i]; }
  for (int i = threadIdx.x; i < 32; i += 512) sb1[i] = b1[i];
  for (int i = threadIdx.x; i < 512; i += 512) { sW2rel[i] = W2_rel[i]; sW2root[i] = W2_root[i]; }
  __syncthreads();
  int b = blockIdx.x;
  unsigned e0 = bucketStart[b], n = bucketTotal[b];
  unsigned i = threadIdx.x;
  bool valid = i < n;
  unsigned p = valid ? packed[e0 + i] : 0u;
  while (valid) {
    unsigned inext = i + 512;
    bool vnext = inext < n;
    unsigned pn = vnext ? packed[e0 + inext] : 0u;
    int s = (int)(p >> BSH), dl = (int)(p & BMASK);
    float4 v = xp[s];
    atomicAdd(&agg[dl * 5 + 0], v.x);
    atomicAdd(&agg[dl * 5 + 1], v.y);
    atomicAdd(&agg[dl * 5 + 2], v.z);
    i = inext; p = pn; valid = vnext;
  }
  __syncthreads();
  int t = threadIdx.x;
  int node = b * 256 + t;
  if (t < 256 && node < N_NODES) {
    float a0 = agg[t * 5], a1 = agg[t * 5 + 1], a2 = agg[t * 5 + 2];
    float4 xv = xp[node];
    float h[32];
#pragma unroll
    for (int k = 0; k < 32; k++) {
      float v = sW1rel[3 * k] * a0 + sW1rel[3 * k + 1] * a1 + sW1rel[3 * k + 2] * a2 +
                sW1root[3 * k] * xv.x + sW1root[3 * k + 1] * xv.y + sW1root[3 * k + 2] * xv.z +
                sb1[k];
      h[k] = fmaxf(v, 0.f);
    }
    float t2v[16], r2v[16];
#pragma unroll
    for (int j = 0; j < 16; j++) {
      float acc = 0.f, accr = 0.f;
#pragma unroll
      for (int k = 0; k < 32; k++) {
        acc += sW2rel[32 * j + k] * h[k];
        accr += sW2root[32 * j + k] * h[k];
      }
      t2v[j] = acc;
      r2v[j] = accr;
    }
    // t2 as fp16, 16 halves = 32B
    unsigned pk[8];
#pragma unroll
    for (int j = 0; j < 8; j++) {
      __half2 h2 = __halves2half2(__float2half_rn(t2v[2 * j]), __float2half_rn(t2v[2 * j + 1]));
      pk[j] = *(unsigned*)&h2;
    }
    uint4* o = (uint4*)&t2h[(size_t)node * 8];
    o[0] = make_uint4(pk[0], pk[1], pk[2], pk[3]);
    o[1] = make_uint4(pk[4], pk[5], pk[6], pk[7]);
    float4* ro = (float4*)&r2[(size_t)node * 16];
#pragma unroll
    for (int j = 0; j < 4; j++)
      ro[j] = make_float4(r2v[4 * j], r2v[4 * j + 1], r2v[4 * j + 2], r2v[4 * j + 3]);
  }
}

__device__ __forceinline__ void half8_unpack(uint4 g, float* f) {
  const __half2* h2 = reinterpret_cast<const __half2*>(&g);
#pragma unroll
  for (int j = 0; j < 4; j++) {
    float2 fj = __half22float2(h2[j]);
    f[2 * j] = fj.x;
    f[2 * j + 1] = fj.y;
  }
}

// ---------- layer 2: two 8-feature gather passes over fp16 t2 ----------
__global__ __launch_bounds__(512) void layer2_kernel(
    const unsigned* __restrict__ packed, const unsigned* __restrict__ bucketStart,
    const unsigned* __restrict__ bucketTotal,
    const unsigned* __restrict__ t2h, const float* __restrict__ r2,
    const float* __restrict__ b2,
    const float* __restrict__ W3_rel, const float* __restrict__ W3_root,
    unsigned* __restrict__ t3h, float* __restrict__ r3) {
  __shared__ float agg[256 * 17];
  __shared__ float sW3rel[128], sW3root[128], sb2[16];
  for (int i = threadIdx.x; i < 256 * 17; i += 512) agg[i] = 0.f;
  for (int i = threadIdx.x; i < 128; i += 512) { sW3rel[i] = W3_rel[i]; sW3root[i] = W3_root[i]; }
  if (threadIdx.x < 16) sb2[threadIdx.x] = b2[threadIdx.x];
  __syncthreads();
  int b = blockIdx.x;
  unsigned e0 = bucketStart[b], n = bucketTotal[b];
  // pass A: features 0..7 (hot set = 3.2 MB)
  {
    unsigned i = threadIdx.x;
    bool valid = i < n;
    unsigned p = valid ? packed[e0 + i] : 0u;
    while (valid) {
      unsigned inext = i + 512;
      bool vnext = inext < n;
      unsigned pn = vnext ? packed[e0 + inext] : 0u;
      int s = (int)(p >> BSH), dl = (int)(p & BMASK);
      uint4 g = *(const uint4*)&t2h[(size_t)s * 8];
      float f[8];
      half8_unpack(g, f);
      int a = dl * 17;
#pragma unroll
      for (int j = 0; j < 8; j++) atomicAdd(&agg[a + j], f[j]);
      i = inext; p = pn; valid = vnext;
    }
  }
  // pass B: features 8..15
  {
    unsigned i = threadIdx.x;
    bool valid = i < n;
    unsigned p = valid ? packed[e0 + i] : 0u;
    while (valid) {
      unsigned inext = i + 512;
      bool vnext = inext < n;
      unsigned pn = vnext ? packed[e0 + inext] : 0u;
      int s = (int)(p >> BSH), dl = (int)(p & BMASK);
      uint4 g = *(const uint4*)&t2h[(size_t)s * 8 + 4];
      float f[8];
      half8_unpack(g, f);
      int a = dl * 17 + 8;
#pragma unroll
      for (int j = 0; j < 8; j++) atomicAdd(&agg[a + j], f[j]);
      i = inext; p = pn; valid = vnext;
    }
  }
  __syncthreads();
  int t = threadIdx.x;
  int node = b * 256 + t;
  if (t < 256 && node < N_NODES) {
    size_t base = (size_t)node * 16;
    float h[16];
#pragma unroll
    for (int j = 0; j < 16; j++) h[j] = fmaxf(agg[t * 17 + j] + sb2[j] + r2[base + j], 0.f);
    float t3v[8], r3v[8];
#pragma unroll
    for (int j = 0; j < 8; j++) {
      float a3 = 0.f, ar = 0.f;
#pragma unroll
      for (int k = 0; k < 16; k++) {
        a3 += sW3rel[16 * j + k] * h[k];
        ar += sW3root[16 * j + k] * h[k];
      }
      t3v[j] = a3;
      r3v[j] = ar;
    }
    unsigned pk[4];
#pragma unroll
    for (int j = 0; j < 4; j++) {
      __half2 h2 = __halves2half2(__float2half_rn(t3v[2 * j]), __float2half_rn(t3v[2 * j + 1]));
      pk[j] = *(unsigned*)&h2;
    }
    *(uint4*)&t3h[(size_t)node * 4] = make_uint4(pk[0], pk[1], pk[2], pk[3]);
    float4* ro = (float4*)&r3[(size_t)node * 8];
    ro[0] = make_float4(r3v[0], r3v[1], r3v[2], r3v[3]);
    ro[1] = make_float4(r3v[4], r3v[5], r3v[6], r3v[7]);
  }
}

// ---------- layer 3: gather fp16 t3 (3.2 MB hot set), fused relu + pooled max ----------
__global__ __launch_bounds__(512) void layer3_kernel(
    const unsigned* __restrict__ packed, const unsigned* __restrict__ bucketStart,
    const unsigned* __restrict__ bucketTotal,
    const unsigned* __restrict__ t3h, const float* __restrict__ r3,
    const float* __restrict__ b3,
    const int* __restrict__ batch, unsigned* __restrict__ pooled) {
  __shared__ float agg[256 * 9];
  __shared__ float sb3[8];
  for (int i = threadIdx.x; i < 256 * 9; i += 512) agg[i] = 0.f;
  if (threadIdx.x < 8) sb3[threadIdx.x] = b3[threadIdx.x];
  __syncthreads();
  int b = blockIdx.x;
  unsigned e0 = bucketStart[b], n = bucketTotal[b];
  unsigned i = threadIdx.x;
  bool valid = i < n;
  unsigned p = valid ? packed[e0 + i] : 0u;
  while (valid) {
    unsigned inext = i + 512;
    bool vnext = inext < n;
    unsigned pn = vnext ? packed[e0 + inext] : 0u;
    int s = (int)(p >> BSH), dl = (int)(p & BMASK);
    uint4 g = *(const uint4*)&t3h[(size_t)s * 4];
    float f[8];
    half8_unpack(g, f);
    int a = dl * 9;
#pragma unroll
    for (int j = 0; j < 8; j++) atomicAdd(&agg[a + j], f[j]);
    i = inext; p = pn; valid = vnext;
  }
  __syncthreads();
  int t = threadIdx.x;
  int node = b * 256 + t;
  if (t < 256 && node < N_NODES) {
    int g = batch[node];
    const float4* rr = (const float4*)&r3[(size_t)node * 8];
    float4 r0 = rr[0], r1 = rr[1];
    float r[8] = {r0.x, r0.y, r0.z, r0.w, r1.x, r1.y, r1.z, r1.w};
#pragma unroll
    for (int f = 0; f < 8; f++) {
      float h = fmaxf(agg[t * 9 + f] + sb3[f] + r[f], 0.f);
      atomicMax(&pooled[8 * g + f], __float_as_uint(h));  // relu>=0: uint order == float order
    }
  }
}

__global__ __launch_bounds__(256) void final_kernel(
    const unsigned* __restrict__ pooled, const float* __restrict__ W_lin,
    const float* __restrict__ b_lin, float* __restrict__ out) {
  int g = blockIdx.x * blockDim.x + threadIdx.x;
  if (g >= N_GRAPHS) return;
  float acc = b_lin[0];
#pragma unroll
  for (int f = 0; f < 8; f++) acc += __uint_as_float(pooled[8 * g + f]) * W_lin[f];
  out[g] = acc;
}

extern "C" void kernel_launch(void* const* d_in, const int* in_sizes, int n_in,
                              void* d_out, int out_size, void* d_ws, size_t ws_size,
                              hipStream_t stream) {
  const float* x = (const float*)d_in[0];
  const int* ei = (const int*)d_in[1];
  const int* src = ei;
  const int* dst = ei + N_EDGES;
  const int* batch = (const int*)d_in[2];
  const float* W1_rel = (const float*)d_in[3];
  const float* b1 = (const float*)d_in[4];
  const float* W1_root = (const float*)d_in[5];
  const float* W2_rel = (const float*)d_in[6];
  const float* b2 = (const float*)d_in[7];
  const float* W2_root = (const float*)d_in[8];
  const float* W3_rel = (const float*)d_in[9];
  const float* b3 = (const float*)d_in[10];
  const float* W3_root = (const float*)d_in[11];
  const float* W_lin = (const float*)d_in[12];
  const float* b_lin = (const float*)d_in[13];
  float* out = (float*)d_out;

  // ---- workspace layout (bytes) ----
  char* ws = (char*)d_ws;
  unsigned* packed = (unsigned*)(ws + 0);              // 25,600,000
  unsigned* t2h = (unsigned*)(ws + 25600000);          // 6,400,000 (fp16 x16/node)
  unsigned* H = (unsigned*)(ws + 25600000);            // alias: 2,446,096, dead before t2h written
  float* r2 = (float*)(ws + 32000000);                 // 12,800,000
  unsigned* t3h = (unsigned*)(ws + 44800000);          // 3,200,000 (fp16 x8/node)
  float* r3 = (float*)(ws + 48000000);                 // 6,400,000
  float4* xpad = (float4*)(ws + 54400000);             // 3,200,000
  unsigned* pooled = (unsigned*)(ws + 57600000);       // 16,384
  unsigned* bucketTotal = (unsigned*)(ws + 57616384);  // 3,136
  unsigned* bucketStart = (unsigned*)(ws + 57619520);  // 3,128

  hipMemsetAsync(pooled, 0, N_GRAPHS * 8 * sizeof(unsigned), stream);

  xpad_kernel<<<(N_NODES + 255) / 256, 256, 0, stream>>>(x, xpad);
  // partition (counting sort by dst bucket; coalesced H; LDS-local sort for writes)
  count_kernel<<<NCH, 256, 0, stream>>>(dst, H);
  scan_bins_kernel<<<(NB + 255) / 256, 256, 0, stream>>>(H, bucketTotal);
  scan_total_kernel<<<1, 1024, 0, stream>>>(bucketTotal, bucketStart);
  scatter_sorted_kernel<<<NCH, 256, 0, stream>>>(src, dst, H, bucketStart, packed);

  layer1_kernel<<<NB, 512, 0, stream>>>(packed, bucketStart, bucketTotal, xpad,
                                        W1_rel, b1, W1_root, W2_rel, W2_root, t2h, r2);
  layer2_kernel<<<NB, 512, 0, stream>>>(packed, bucketStart, bucketTotal,
                                        t2h, r2, b2, W3_rel, W3_root, t3h, r3);
  layer3_kernel<<<NB, 512, 0, stream>>>(packed, bucketStart, bucketTotal,
                                        t3h, r3, b3, batch, pooled);
  final_kernel<<<(N_GRAPHS + 255) / 256, 256, 0, stream>>>(pooled, W_lin, b_lin, out);
}

// Round 4
// 1392.159 us; speedup vs baseline: 2.8427x; 1.2072x over previous
//
#include <hip/hip_runtime.h>
#include <hip/hip_fp16.h>

#define N_NODES 200000
#define N_EDGES 6400000
#define N_GRAPHS 512

#define NB 1563       // dst buckets of 128 nodes: ceil(200000/128)
#define BSH 7
#define BMASK 127
#define NCH 1563      // edge chunks: 1563*4096 = 6,402,048 >= 6.4M
#define CHUNK 4096
#define NGRP 8        // chunk groups for parallel scan
#define CPG 196       // chunks per group: 8*196 = 1568 >= 1563

// ---------- partition: counting sort of edges by dst>>7 ----------
// H layout TRANSPOSED: H[c*NB + b]

__global__ __launch_bounds__(256) void count_kernel(const int* __restrict__ dst,
                                                    unsigned* __restrict__ H) {
  __shared__ unsigned hist[NB];
  for (int i = threadIdx.x; i < NB; i += 256) hist[i] = 0;
  __syncthreads();
  int c = blockIdx.x;
  long e0 = (long)c * CHUNK;
  long rem = (long)N_EDGES - e0;
  int n = rem > CHUNK ? CHUNK : (rem > 0 ? (int)rem : 0);
  for (int i = threadIdx.x; i < n; i += 256) atomicAdd(&hist[dst[e0 + i] >> BSH], 1u);
  __syncthreads();
  for (int i = threadIdx.x; i < NB; i += 256) H[(size_t)c * NB + i] = hist[i];
}

// per-(group,bucket) scan over that group's chunks; H[c][b] -> within-group offset
__global__ __launch_bounds__(256) void scan_bins1_kernel(unsigned* __restrict__ H,
                                                         unsigned* __restrict__ P) {
  int b = blockIdx.x * 256 + threadIdx.x;
  int g = blockIdx.y;
  if (b >= NB) return;
  int c0 = g * CPG, c1 = min(NCH, (g + 1) * CPG);
  unsigned run = 0;
  for (int c = c0; c < c1; c++) {
    unsigned t = H[(size_t)c * NB + b];
    H[(size_t)c * NB + b] = run;
    run += t;
  }
  P[(size_t)g * NB + b] = run;
}

// scan P over groups per bucket; P[g][b] -> group base; bucketTotal[b] = total
__global__ __launch_bounds__(256) void scan_bins2_kernel(unsigned* __restrict__ P,
                                                         unsigned* __restrict__ bucketTotal) {
  int b = blockIdx.x * 256 + threadIdx.x;
  if (b >= NB) return;
  unsigned run = 0;
  for (int g = 0; g < NGRP; g++) {
    unsigned t = P[(size_t)g * NB + b];
    P[(size_t)g * NB + b] = run;
    run += t;
  }
  bucketTotal[b] = run;
}

// exclusive scan of bucketTotal[NB] -> bucketStart (one block, segment-serial)
#define SEG 7  // 256*7 = 1792 >= NB
__global__ __launch_bounds__(256) void scan_total_kernel(const unsigned* __restrict__ bucketTotal,
                                                         unsigned* __restrict__ bucketStart) {
  __shared__ unsigned sv[256 * SEG];
  __shared__ unsigned partial[256];
  int t = threadIdx.x;
  for (int i = t; i < 256 * SEG; i += 256) sv[i] = (i < NB) ? bucketTotal[i] : 0u;
  __syncthreads();
  unsigned sum = 0;
#pragma unroll
  for (int k = 0; k < SEG; k++) sum += sv[t * SEG + k];
  partial[t] = sum;
  __syncthreads();
  for (int off = 1; off < 256; off <<= 1) {
    unsigned add = (t >= off) ? partial[t - off] : 0u;
    __syncthreads();
    partial[t] += add;
    __syncthreads();
  }
  unsigned run = partial[t] - sum;
#pragma unroll
  for (int k = 0; k < SEG; k++) {
    unsigned w = sv[t * SEG + k];
    sv[t * SEG + k] = run;
    run += w;
  }
  __syncthreads();
  for (int i = t; i < NB; i += 256) bucketStart[i] = sv[i];
}

// chunk-local LDS counting sort, then coalesced-run writes of packed
__global__ __launch_bounds__(256) void scatter_sorted_kernel(
    const int* __restrict__ src, const int* __restrict__ dst,
    const unsigned* __restrict__ H, const unsigned* __restrict__ P,
    const unsigned* __restrict__ bucketStart, unsigned* __restrict__ packed) {
  __shared__ unsigned ssort[CHUNK];        // 16 KB
  __shared__ unsigned short sbort[CHUNK];  // 8 KB
  __shared__ unsigned hist[2048];          // 8 KB (NB padded)
  __shared__ unsigned cur[2048];           // 8 KB
  __shared__ unsigned partial[256];
  int t = threadIdx.x;
  int c = blockIdx.x;
  int g = c / CPG;
  long e0 = (long)c * CHUNK;
  long rem = (long)N_EDGES - e0;
  int n = rem > CHUNK ? CHUNK : (rem > 0 ? (int)rem : 0);
  for (int i = t; i < 2048; i += 256) hist[i] = 0;
  __syncthreads();
  for (int i = t; i < n; i += 256) atomicAdd(&hist[dst[e0 + i] >> BSH], 1u);
  __syncthreads();
  unsigned a[8], sum = 0;
#pragma unroll
  for (int k = 0; k < 8; k++) { a[k] = hist[8 * t + k]; sum += a[k]; }
  partial[t] = sum;
  __syncthreads();
  for (int off = 1; off < 256; off <<= 1) {
    unsigned add = (t >= off) ? partial[t - off] : 0u;
    __syncthreads();
    partial[t] += add;
    __syncthreads();
  }
  unsigned run = partial[t] - sum;
#pragma unroll
  for (int k = 0; k < 8; k++) {
    hist[8 * t + k] = run;
    cur[8 * t + k] = run;
    run += a[k];
  }
  __syncthreads();
  for (int i = t; i < n; i += 256) {
    int d = dst[e0 + i], s = src[e0 + i];
    int b = d >> BSH;
    unsigned r = atomicAdd(&cur[b], 1u);
    ssort[r] = ((unsigned)s << BSH) | (unsigned)(d & BMASK);
    sbort[r] = (unsigned short)b;
  }
  __syncthreads();
  for (int b = t; b < NB; b += 256)
    cur[b] = bucketStart[b] + P[(size_t)g * NB + b] + H[(size_t)c * NB + b] - hist[b];
  __syncthreads();
  for (int j = t; j < n; j += 256) packed[cur[sbort[j]] + j] = ssort[j];
}

// ---------- xpad ----------
__global__ __launch_bounds__(256) void xpad_kernel(const float* __restrict__ x,
                                                   float4* __restrict__ xp) {
  int n = blockIdx.x * 256 + threadIdx.x;
  if (n >= N_NODES) return;
  xp[n] = make_float4(x[3 * n], x[3 * n + 1], x[3 * n + 2], 0.f);
}

__device__ __forceinline__ void half8_unpack(uint4 g, float* f) {
  const __half2* h2 = reinterpret_cast<const __half2*>(&g);
#pragma unroll
  for (int j = 0; j < 4; j++) {
    float2 fj = __half22float2(h2[j]);
    f[2 * j] = fj.x;
    f[2 * j + 1] = fj.y;
  }
}

// ---------- layer 1 ----------
__global__ __launch_bounds__(256) void layer1_kernel(
    const unsigned* __restrict__ packed, const unsigned* __restrict__ bucketStart,
    const unsigned* __restrict__ bucketTotal, const float4* __restrict__ xp,
    const float* __restrict__ W1_rel, const float* __restrict__ b1,
    const float* __restrict__ W1_root,
    const float* __restrict__ W2_rel, const float* __restrict__ W2_root,
    uint4* __restrict__ t2a, uint4* __restrict__ t2b, float* __restrict__ r2) {
  __shared__ float agg[128 * 5];
  __shared__ float sW1rel[96], sW1root[96], sb1[32], sW2rel[512], sW2root[512];
  for (int i = threadIdx.x; i < 128 * 5; i += 256) agg[i] = 0.f;
  for (int i = threadIdx.x; i < 96; i += 256) { sW1rel[i] = W1_rel[i]; sW1root[i] = W1_root[i]; }
  for (int i = threadIdx.x; i < 32; i += 256) sb1[i] = b1[i];
  for (int i = threadIdx.x; i < 512; i += 256) { sW2rel[i] = W2_rel[i]; sW2root[i] = W2_root[i]; }
  __syncthreads();
  int blk = blockIdx.x;
  unsigned e0 = bucketStart[blk], n = bucketTotal[blk];
  // 2-ahead pipeline: packed 2 ahead, gather 1 ahead
  unsigned i0 = threadIdx.x;
  bool v0 = i0 < n;
  unsigned p0 = v0 ? packed[e0 + i0] : 0u;
  unsigned i1 = i0 + 256;
  bool v1 = i1 < n;
  unsigned p1 = v1 ? packed[e0 + i1] : 0u;
  float4 g0 = v0 ? xp[p0 >> BSH] : make_float4(0, 0, 0, 0);
  while (v0) {
    float4 g1 = v1 ? xp[p1 >> BSH] : make_float4(0, 0, 0, 0);
    unsigned i2 = i1 + 256;
    bool v2 = i2 < n;
    unsigned p2 = v2 ? packed[e0 + i2] : 0u;
    int dl = (int)(p0 & BMASK);
    atomicAdd(&agg[dl * 5 + 0], g0.x);
    atomicAdd(&agg[dl * 5 + 1], g0.y);
    atomicAdd(&agg[dl * 5 + 2], g0.z);
    p0 = p1; v0 = v1; g0 = g1;
    i1 = i2; p1 = p2; v1 = v2;
  }
  __syncthreads();
  int t = threadIdx.x;
  int node = blk * 128 + (t >> 1);
  int half = t & 1;
  if (node < N_NODES) {
    int ln = t >> 1;
    float a0 = agg[ln * 5], a1 = agg[ln * 5 + 1], a2 = agg[ln * 5 + 2];
    float4 xv = xp[node];
    float h[32];
#pragma unroll
    for (int k = 0; k < 32; k++) {
      float v = sW1rel[3 * k] * a0 + sW1rel[3 * k + 1] * a1 + sW1rel[3 * k + 2] * a2 +
                sW1root[3 * k] * xv.x + sW1root[3 * k + 1] * xv.y + sW1root[3 * k + 2] * xv.z +
                sb1[k];
      h[k] = fmaxf(v, 0.f);
    }
    float tv[8], rv[8];
    int jb = half * 8;
#pragma unroll
    for (int j = 0; j < 8; j++) {
      float acc = 0.f, accr = 0.f;
#pragma unroll
      for (int k = 0; k < 32; k++) {
        acc += sW2rel[32 * (jb + j) + k] * h[k];
        accr += sW2root[32 * (jb + j) + k] * h[k];
      }
      tv[j] = acc;
      rv[j] = accr;
    }
    unsigned pk[4];
#pragma unroll
    for (int j = 0; j < 4; j++) {
      __half2 h2 = __halves2half2(__float2half_rn(tv[2 * j]), __float2half_rn(tv[2 * j + 1]));
      pk[j] = *(unsigned*)&h2;
    }
    uint4 rec = make_uint4(pk[0], pk[1], pk[2], pk[3]);
    if (half == 0) t2a[node] = rec; else t2b[node] = rec;
    float4* ro = (float4*)&r2[(size_t)node * 16 + jb];
    ro[0] = make_float4(rv[0], rv[1], rv[2], rv[3]);
    ro[1] = make_float4(rv[4], rv[5], rv[6], rv[7]);
  }
}

// ---------- layer 2: two 8-feature gather passes over split fp16 arrays ----------
__global__ __launch_bounds__(256) void layer2_kernel(
    const unsigned* __restrict__ packed, const unsigned* __restrict__ bucketStart,
    const unsigned* __restrict__ bucketTotal,
    const uint4* __restrict__ t2a, const uint4* __restrict__ t2b,
    const float* __restrict__ r2, const float* __restrict__ b2,
    const float* __restrict__ W3_rel, const float* __restrict__ W3_root,
    uint4* __restrict__ t3h, float* __restrict__ r3) {
  __shared__ float agg[128 * 17];
  __shared__ float sW3rel[128], sW3root[128], sb2[16];
  for (int i = threadIdx.x; i < 128 * 17; i += 256) agg[i] = 0.f;
  for (int i = threadIdx.x; i < 128; i += 256) { sW3rel[i] = W3_rel[i]; sW3root[i] = W3_root[i]; }
  if (threadIdx.x < 16) sb2[threadIdx.x] = b2[threadIdx.x];
  __syncthreads();
  int blk = blockIdx.x;
  unsigned e0 = bucketStart[blk], n = bucketTotal[blk];
#pragma unroll
  for (int pass = 0; pass < 2; pass++) {
    const uint4* tsrc = pass == 0 ? t2a : t2b;
    int aoff = pass * 8;
    unsigned i0 = threadIdx.x;
    bool v0 = i0 < n;
    unsigned p0 = v0 ? packed[e0 + i0] : 0u;
    unsigned i1 = i0 + 256;
    bool v1 = i1 < n;
    unsigned p1 = v1 ? packed[e0 + i1] : 0u;
    uint4 g0 = v0 ? tsrc[p0 >> BSH] : make_uint4(0, 0, 0, 0);
    while (v0) {
      uint4 g1 = v1 ? tsrc[p1 >> BSH] : make_uint4(0, 0, 0, 0);
      unsigned i2 = i1 + 256;
      bool v2 = i2 < n;
      unsigned p2 = v2 ? packed[e0 + i2] : 0u;
      int a = (int)(p0 & BMASK) * 17 + aoff;
      float f[8];
      half8_unpack(g0, f);
#pragma unroll
      for (int j = 0; j < 8; j++) atomicAdd(&agg[a + j], f[j]);
      p0 = p1; v0 = v1; g0 = g1;
      i1 = i2; p1 = p2; v1 = v2;
    }
    __syncthreads();
  }
  int t = threadIdx.x;
  int node = blk * 128 + (t >> 1);
  int half = t & 1;
  if (node < N_NODES) {
    int ln = t >> 1;
    size_t base = (size_t)node * 16;
    float h[16];
#pragma unroll
    for (int j = 0; j < 16; j++) h[j] = fmaxf(agg[ln * 17 + j] + sb2[j] + r2[base + j], 0.f);
    const float* W = half == 0 ? sW3rel : sW3root;
    float o[8];
#pragma unroll
    for (int j = 0; j < 8; j++) {
      float acc = 0.f;
#pragma unroll
      for (int k = 0; k < 16; k++) acc += W[16 * j + k] * h[k];
      o[j] = acc;
    }
    if (half == 0) {
      unsigned pk[4];
#pragma unroll
      for (int j = 0; j < 4; j++) {
        __half2 h2 = __halves2half2(__float2half_rn(o[2 * j]), __float2half_rn(o[2 * j + 1]));
        pk[j] = *(unsigned*)&h2;
      }
      t3h[node] = make_uint4(pk[0], pk[1], pk[2], pk[3]);
    } else {
      float4* ro = (float4*)&r3[(size_t)node * 8];
      ro[0] = make_float4(o[0], o[1], o[2], o[3]);
      ro[1] = make_float4(o[4], o[5], o[6], o[7]);
    }
  }
}

// ---------- layer 3 ----------
__global__ __launch_bounds__(256) void layer3_kernel(
    const unsigned* __restrict__ packed, const unsigned* __restrict__ bucketStart,
    const unsigned* __restrict__ bucketTotal,
    const uint4* __restrict__ t3h, const float* __restrict__ r3,
    const float* __restrict__ b3,
    const int* __restrict__ batch, unsigned* __restrict__ pooled) {
  __shared__ float agg[128 * 9];
  __shared__ float sb3[8];
  for (int i = threadIdx.x; i < 128 * 9; i += 256) agg[i] = 0.f;
  if (threadIdx.x < 8) sb3[threadIdx.x] = b3[threadIdx.x];
  __syncthreads();
  int blk = blockIdx.x;
  unsigned e0 = bucketStart[blk], n = bucketTotal[blk];
  unsigned i0 = threadIdx.x;
  bool v0 = i0 < n;
  unsigned p0 = v0 ? packed[e0 + i0] : 0u;
  unsigned i1 = i0 + 256;
  bool v1 = i1 < n;
  unsigned p1 = v1 ? packed[e0 + i1] : 0u;
  uint4 g0 = v0 ? t3h[p0 >> BSH] : make_uint4(0, 0, 0, 0);
  while (v0) {
    uint4 g1 = v1 ? t3h[p1 >> BSH] : make_uint4(0, 0, 0, 0);
    unsigned i2 = i1 + 256;
    bool v2 = i2 < n;
    unsigned p2 = v2 ? packed[e0 + i2] : 0u;
    int a = (int)(p0 & BMASK) * 9;
    float f[8];
    half8_unpack(g0, f);
#pragma unroll
    for (int j = 0; j < 8; j++) atomicAdd(&agg[a + j], f[j]);
    p0 = p1; v0 = v1; g0 = g1;
    i1 = i2; p1 = p2; v1 = v2;
  }
  __syncthreads();
  int t = threadIdx.x;
  int node = blk * 128 + (t >> 1);
  int half = t & 1;
  if (node < N_NODES) {
    int ln = t >> 1;
    int g = batch[node];
    float4 r = *(const float4*)&r3[(size_t)node * 8 + half * 4];
    float rr[4] = {r.x, r.y, r.z, r.w};
#pragma unroll
    for (int f = 0; f < 4; f++) {
      int fi = half * 4 + f;
      float h = fmaxf(agg[ln * 9 + fi] + sb3[fi] + rr[f], 0.f);
      atomicMax(&pooled[8 * g + fi], __float_as_uint(h));  // relu>=0: uint order==float order
    }
  }
}

__global__ __launch_bounds__(256) void final_kernel(
    const unsigned* __restrict__ pooled, const float* __restrict__ W_lin,
    const float* __restrict__ b_lin, float* __restrict__ out) {
  int g = blockIdx.x * blockDim.x + threadIdx.x;
  if (g >= N_GRAPHS) return;
  float acc = b_lin[0];
#pragma unroll
  for (int f = 0; f < 8; f++) acc += __uint_as_float(pooled[8 * g + f]) * W_lin[f];
  out[g] = acc;
}

extern "C" void kernel_launch(void* const* d_in, const int* in_sizes, int n_in,
                              void* d_out, int out_size, void* d_ws, size_t ws_size,
                              hipStream_t stream) {
  const float* x = (const float*)d_in[0];
  const int* ei = (const int*)d_in[1];
  const int* src = ei;
  const int* dst = ei + N_EDGES;
  const int* batch = (const int*)d_in[2];
  const float* W1_rel = (const float*)d_in[3];
  const float* b1 = (const float*)d_in[4];
  const float* W1_root = (const float*)d_in[5];
  const float* W2_rel = (const float*)d_in[6];
  const float* b2 = (const float*)d_in[7];
  const float* W2_root = (const float*)d_in[8];
  const float* W3_rel = (const float*)d_in[9];
  const float* b3 = (const float*)d_in[10];
  const float* W3_root = (const float*)d_in[11];
  const float* W_lin = (const float*)d_in[12];
  const float* b_lin = (const float*)d_in[13];
  float* out = (float*)d_out;

  // ---- workspace layout (bytes) ----
  char* ws = (char*)d_ws;
  unsigned* packed = (unsigned*)(ws + 0);              // 25,600,000
  uint4* t2a = (uint4*)(ws + 25600000);                // 3,200,000 (fp16 feat 0-7)
  uint4* t2b = (uint4*)(ws + 28800000);                // 3,200,000 (fp16 feat 8-15)
  float* r2 = (float*)(ws + 32000000);                 // 12,800,000
  unsigned* H = (unsigned*)(ws + 25600000);            // alias: 9,771,876; dead before layer1
  uint4* t3h = (uint4*)(ws + 44800000);                // 3,200,000 (fp16 x8)
  float* r3 = (float*)(ws + 48000000);                 // 6,400,000
  float4* xpad = (float4*)(ws + 54400000);             // 3,200,000
  unsigned* pooled = (unsigned*)(ws + 57600000);       // 16,384
  unsigned* bucketTotal = (unsigned*)(ws + 57616384);  // 6,400
  unsigned* bucketStart = (unsigned*)(ws + 57622784);  // 6,400
  unsigned* P = (unsigned*)(ws + 57629184);            // 50,016 (group partials)

  hipMemsetAsync(pooled, 0, N_GRAPHS * 8 * sizeof(unsigned), stream);

  xpad_kernel<<<(N_NODES + 255) / 256, 256, 0, stream>>>(x, xpad);
  count_kernel<<<NCH, 256, 0, stream>>>(dst, H);
  scan_bins1_kernel<<<dim3((NB + 255) / 256, NGRP), 256, 0, stream>>>(H, P);
  scan_bins2_kernel<<<(NB + 255) / 256, 256, 0, stream>>>(P, bucketTotal);
  scan_total_kernel<<<1, 256, 0, stream>>>(bucketTotal, bucketStart);
  scatter_sorted_kernel<<<NCH, 256, 0, stream>>>(src, dst, H, P, bucketStart, packed);

  layer1_kernel<<<NB, 256, 0, stream>>>(packed, bucketStart, bucketTotal, xpad,
                                        W1_rel, b1, W1_root, W2_rel, W2_root, t2a, t2b, r2);
  layer2_kernel<<<NB, 256, 0, stream>>>(packed, bucketStart, bucketTotal,
                                        t2a, t2b, r2, b2, W3_rel, W3_root, t3h, r3);
  layer3_kernel<<<NB, 256, 0, stream>>>(packed, bucketStart, bucketTotal,
                                        t3h, r3, b3, batch, pooled);
  final_kernel<<<(N_GRAPHS + 255) / 256, 256, 0, stream>>>(pooled, W_lin, b_lin, out);
}

// Round 5
// 1310.460 us; speedup vs baseline: 3.0199x; 1.0623x over previous
//
#include <hip/hip_runtime.h>
#include <hip/hip_fp16.h>

#define N_NODES 200000
#define N_EDGES 6400000
#define N_GRAPHS 512

#define NB 3125      // 64-node dst buckets: 3125*64 = 200000 exactly
#define NCH 3125     // edge chunks: 3125*2048 = 6,400,000 exactly
#define CHUNK 2048
#define NGRP 25      // chunk groups for parallel scan
#define CPG 125      // chunks per group
#define SENT 64u     // sentinel packed entry: src=0, dl=64 (LDS trash row)

// ---------- partition: counting sort of edges by dst>>6 ----------
// H (ushort) TRANSPOSED: H[c*NB + b]

__global__ __launch_bounds__(256) void count_kernel(const int* __restrict__ dst,
                                                    unsigned short* __restrict__ H) {
  __shared__ unsigned hist[NB];
  for (int i = threadIdx.x; i < NB; i += 256) hist[i] = 0;
  __syncthreads();
  int c = blockIdx.x;
  long e0 = (long)c * CHUNK;
  for (int i = threadIdx.x; i < CHUNK; i += 256) atomicAdd(&hist[dst[e0 + i] >> 6], 1u);
  __syncthreads();
  for (int i = threadIdx.x; i < NB; i += 256) H[(size_t)c * NB + i] = (unsigned short)hist[i];
}

// per-(group,bucket) scan; H[c][b] -> within-group offset; P[g][b] = group total
__global__ __launch_bounds__(256) void scan_bins1_kernel(unsigned short* __restrict__ H,
                                                         unsigned* __restrict__ P) {
  int b = blockIdx.x * 256 + threadIdx.x;
  int g = blockIdx.y;
  if (b >= NB) return;
  unsigned run = 0;
  for (int c = g * CPG; c < (g + 1) * CPG; c++) {
    unsigned t = H[(size_t)c * NB + b];
    H[(size_t)c * NB + b] = (unsigned short)run;
    run += t;
  }
  P[(size_t)g * NB + b] = run;
}

// scan P over groups; P[g][b] -> group base; bucketTotal[b] = raw total
__global__ __launch_bounds__(256) void scan_bins2_kernel(unsigned* __restrict__ P,
                                                         unsigned* __restrict__ bucketTotal) {
  int b = blockIdx.x * 256 + threadIdx.x;
  if (b >= NB) return;
  unsigned run = 0;
  for (int g = 0; g < NGRP; g++) {
    unsigned t = P[(size_t)g * NB + b];
    P[(size_t)g * NB + b] = run;
    run += t;
  }
  bucketTotal[b] = run;
}

// exclusive scan of PADDED totals -> bucketStart (each bucket start ×4 edges, 16B aligned)
#define SEG 13  // 256*13 = 3328 >= NB
__global__ __launch_bounds__(256) void scan_total_kernel(const unsigned* __restrict__ bucketTotal,
                                                         unsigned* __restrict__ bucketStart) {
  __shared__ unsigned sv[256 * SEG];
  __shared__ unsigned partial[256];
  int t = threadIdx.x;
  for (int i = t; i < 256 * SEG; i += 256)
    sv[i] = (i < NB) ? ((bucketTotal[i] + 3u) & ~3u) : 0u;
  __syncthreads();
  unsigned sum = 0;
#pragma unroll
  for (int k = 0; k < SEG; k++) sum += sv[t * SEG + k];
  partial[t] = sum;
  __syncthreads();
  for (int off = 1; off < 256; off <<= 1) {
    unsigned add = (t >= off) ? partial[t - off] : 0u;
    __syncthreads();
    partial[t] += add;
    __syncthreads();
  }
  unsigned run = partial[t] - sum;
#pragma unroll
  for (int k = 0; k < SEG; k++) {
    unsigned w = sv[t * SEG + k];
    sv[t * SEG + k] = run;
    run += w;
  }
  __syncthreads();
  for (int i = t; i < NB; i += 256) bucketStart[i] = sv[i];
}

// fill pad slots with sentinel (src=0, dl=64)
__global__ __launch_bounds__(256) void pad_fill_kernel(const unsigned* __restrict__ bucketStart,
                                                       const unsigned* __restrict__ bucketTotal,
                                                       unsigned* __restrict__ packed) {
  int b = blockIdx.x * 256 + threadIdx.x;
  if (b >= NB) return;
  unsigned st = bucketStart[b], raw = bucketTotal[b], pd = (raw + 3u) & ~3u;
  for (unsigned k = raw; k < pd; k++) packed[st + k] = SENT;
}

// chunk-local LDS counting sort, then coalesced-run writes of packed
__global__ __launch_bounds__(256) void scatter_sorted_kernel(
    const int* __restrict__ src, const int* __restrict__ dst,
    const unsigned short* __restrict__ H, const unsigned* __restrict__ P,
    const unsigned* __restrict__ bucketStart, unsigned* __restrict__ packed) {
  __shared__ unsigned ssort[CHUNK];        // 8 KB
  __shared__ unsigned short sbort[CHUNK];  // 4 KB
  __shared__ unsigned hist[3328];          // 13 KB
  __shared__ unsigned cur[3328];           // 13 KB
  __shared__ unsigned partial[256];
  int t = threadIdx.x;
  int c = blockIdx.x;
  int g = c / CPG;
  long e0 = (long)c * CHUNK;
  for (int i = t; i < 3328; i += 256) hist[i] = 0;
  __syncthreads();
  for (int i = t; i < CHUNK; i += 256) atomicAdd(&hist[dst[e0 + i] >> 6], 1u);
  __syncthreads();
  unsigned a[SEG], sum = 0;
#pragma unroll
  for (int k = 0; k < SEG; k++) { a[k] = hist[SEG * t + k]; sum += a[k]; }
  partial[t] = sum;
  __syncthreads();
  for (int off = 1; off < 256; off <<= 1) {
    unsigned add = (t >= off) ? partial[t - off] : 0u;
    __syncthreads();
    partial[t] += add;
    __syncthreads();
  }
  unsigned run = partial[t] - sum;
#pragma unroll
  for (int k = 0; k < SEG; k++) {
    hist[SEG * t + k] = run;
    cur[SEG * t + k] = run;
    run += a[k];
  }
  __syncthreads();
  for (int i = t; i < CHUNK; i += 256) {
    int d = dst[e0 + i], s = src[e0 + i];
    int b = d >> 6;
    unsigned r = atomicAdd(&cur[b], 1u);
    ssort[r] = ((unsigned)s << 7) | (unsigned)(d & 63);
    sbort[r] = (unsigned short)b;
  }
  __syncthreads();
  for (int b = t; b < NB; b += 256)
    cur[b] = bucketStart[b] + P[(size_t)g * NB + b] + H[(size_t)c * NB + b] - hist[b];
  __syncthreads();
  for (int j = t; j < CHUNK; j += 256) packed[cur[sbort[j]] + j] = ssort[j];
}

// ---------- xpad ----------
__global__ __launch_bounds__(256) void xpad_kernel(const float* __restrict__ x,
                                                   float4* __restrict__ xp) {
  int n = blockIdx.x * 256 + threadIdx.x;
  if (n >= N_NODES) return;
  xp[n] = make_float4(x[3 * n], x[3 * n + 1], x[3 * n + 2], 0.f);
}

// ---------- layer 1: 4-wide gather of xpad, LDS agg, fused transform ----------
__global__ __launch_bounds__(256) void layer1_kernel(
    const unsigned* __restrict__ packed, const unsigned* __restrict__ bucketStart,
    const unsigned* __restrict__ bucketTotal, const float4* __restrict__ xp,
    const float* __restrict__ W1_rel, const float* __restrict__ b1,
    const float* __restrict__ W1_root,
    const float* __restrict__ W2_rel, const float* __restrict__ W2_root,
    unsigned* __restrict__ t2h, float* __restrict__ r2) {
  __shared__ float agg[65 * 5];  // row 64 = sentinel trash
  __shared__ float sW1rel[96], sW1root[96], sb1[32], sW2rel[512], sW2root[512];
  for (int i = threadIdx.x; i < 65 * 5; i += 256) agg[i] = 0.f;
  for (int i = threadIdx.x; i < 96; i += 256) { sW1rel[i] = W1_rel[i]; sW1root[i] = W1_root[i]; }
  for (int i = threadIdx.x; i < 32; i += 256) sb1[i] = b1[i];
  for (int i = threadIdx.x; i < 512; i += 256) { sW2rel[i] = W2_rel[i]; sW2root[i] = W2_root[i]; }
  __syncthreads();
  int blk = blockIdx.x;
  unsigned e0 = bucketStart[blk];
  unsigned n = (bucketTotal[blk] + 3u) & ~3u;
  for (unsigned base = threadIdx.x * 4; base < n; base += 1024) {
    uint4 pk = *(const uint4*)&packed[e0 + base];
    float4 g0 = xp[pk.x >> 7], g1 = xp[pk.y >> 7], g2 = xp[pk.z >> 7], g3 = xp[pk.w >> 7];
    int a0 = (int)(pk.x & 127u) * 5, a1 = (int)(pk.y & 127u) * 5;
    int a2 = (int)(pk.z & 127u) * 5, a3 = (int)(pk.w & 127u) * 5;
    atomicAdd(&agg[a0], g0.x); atomicAdd(&agg[a0 + 1], g0.y); atomicAdd(&agg[a0 + 2], g0.z);
    atomicAdd(&agg[a1], g1.x); atomicAdd(&agg[a1 + 1], g1.y); atomicAdd(&agg[a1 + 2], g1.z);
    atomicAdd(&agg[a2], g2.x); atomicAdd(&agg[a2 + 1], g2.y); atomicAdd(&agg[a2 + 2], g2.z);
    atomicAdd(&agg[a3], g3.x); atomicAdd(&agg[a3 + 1], g3.y); atomicAdd(&agg[a3 + 2], g3.z);
  }
  __syncthreads();
  int t = threadIdx.x, ln = t >> 2, q = t & 3;
  int node = blk * 64 + ln;  // 3125*64 == 200000: no bounds check needed
  float A0 = agg[ln * 5], A1 = agg[ln * 5 + 1], A2 = agg[ln * 5 + 2];
  float4 xv = xp[node];
  float h[32];
#pragma unroll
  for (int k = 0; k < 32; k++) {
    float v = sW1rel[3 * k] * A0 + sW1rel[3 * k + 1] * A1 + sW1rel[3 * k + 2] * A2 +
              sW1root[3 * k] * xv.x + sW1root[3 * k + 1] * xv.y + sW1root[3 * k + 2] * xv.z +
              sb1[k];
    h[k] = fmaxf(v, 0.f);
  }
  int jb = q * 4;
  float tv[4], rv[4];
#pragma unroll
  for (int j = 0; j < 4; j++) {
    float acc = 0.f, accr = 0.f;
#pragma unroll
    for (int k = 0; k < 32; k++) {
      acc += sW2rel[32 * (jb + j) + k] * h[k];
      accr += sW2root[32 * (jb + j) + k] * h[k];
    }
    tv[j] = acc;
    rv[j] = accr;
  }
  __half2 p0 = __halves2half2(__float2half_rn(tv[0]), __float2half_rn(tv[1]));
  __half2 p1 = __halves2half2(__float2half_rn(tv[2]), __float2half_rn(tv[3]));
  uint2 rec = make_uint2(*(unsigned*)&p0, *(unsigned*)&p1);
  *(uint2*)&t2h[(size_t)node * 8 + q * 2] = rec;  // interleaved 32B record
  *(float4*)&r2[(size_t)node * 16 + jb] = make_float4(rv[0], rv[1], rv[2], rv[3]);
}

__device__ __forceinline__ void half8_unpack(uint4 g, float* f) {
  const __half2* h2 = reinterpret_cast<const __half2*>(&g);
#pragma unroll
  for (int j = 0; j < 4; j++) {
    float2 fj = __half22float2(h2[j]);
    f[2 * j] = fj.x;
    f[2 * j + 1] = fj.y;
  }
}

// ---------- layer 2: SINGLE pass, 32B interleaved record (same-line MSHR merge) ----------
__global__ __launch_bounds__(256) void layer2_kernel(
    const unsigned* __restrict__ packed, const unsigned* __restrict__ bucketStart,
    const unsigned* __restrict__ bucketTotal,
    const uint4* __restrict__ t2h4, const float* __restrict__ r2,
    const float* __restrict__ b2,
    const float* __restrict__ W3_rel, const float* __restrict__ W3_root,
    unsigned* __restrict__ t3h, float* __restrict__ r3) {
  __shared__ float agg[65 * 17];
  __shared__ float sW3rel[128], sW3root[128], sb2[16];
  for (int i = threadIdx.x; i < 65 * 17; i += 256) agg[i] = 0.f;
  for (int i = threadIdx.x; i < 128; i += 256) { sW3rel[i] = W3_rel[i]; sW3root[i] = W3_root[i]; }
  if (threadIdx.x < 16) sb2[threadIdx.x] = b2[threadIdx.x];
  __syncthreads();
  int blk = blockIdx.x;
  unsigned e0 = bucketStart[blk];
  unsigned n = (bucketTotal[blk] + 3u) & ~3u;
  for (unsigned base = threadIdx.x * 4; base < n; base += 1024) {
    uint4 pk = *(const uint4*)&packed[e0 + base];
    unsigned s0 = pk.x >> 7, s1 = pk.y >> 7, s2 = pk.z >> 7, s3 = pk.w >> 7;
    // both halves of each record: adjacent 16B in the same 64B line -> 1 line-fill/edge
    uint4 ga0 = t2h4[s0 * 2], gb0 = t2h4[s0 * 2 + 1];
    uint4 ga1 = t2h4[s1 * 2], gb1 = t2h4[s1 * 2 + 1];
    uint4 ga2 = t2h4[s2 * 2], gb2 = t2h4[s2 * 2 + 1];
    uint4 ga3 = t2h4[s3 * 2], gb3 = t2h4[s3 * 2 + 1];
    unsigned dls[4] = {pk.x & 127u, pk.y & 127u, pk.z & 127u, pk.w & 127u};
    uint4 gas[4] = {ga0, ga1, ga2, ga3};
    uint4 gbs[4] = {gb0, gb1, gb2, gb3};
#pragma unroll
    for (int e = 0; e < 4; e++) {
      int a = (int)dls[e] * 17;
      float f[8];
      half8_unpack(gas[e], f);
#pragma unroll
      for (int j = 0; j < 8; j++) atomicAdd(&agg[a + j], f[j]);
      half8_unpack(gbs[e], f);
#pragma unroll
      for (int j = 0; j < 8; j++) atomicAdd(&agg[a + 8 + j], f[j]);
    }
  }
  __syncthreads();
  int t = threadIdx.x, ln = t >> 2, q = t & 3;
  int node = blk * 64 + ln;
  const float4* rr = (const float4*)&r2[(size_t)node * 16];
  float h[16];
#pragma unroll
  for (int j = 0; j < 4; j++) {
    float4 r4 = rr[j];
    h[4 * j + 0] = fmaxf(agg[ln * 17 + 4 * j + 0] + sb2[4 * j + 0] + r4.x, 0.f);
    h[4 * j + 1] = fmaxf(agg[ln * 17 + 4 * j + 1] + sb2[4 * j + 1] + r4.y, 0.f);
    h[4 * j + 2] = fmaxf(agg[ln * 17 + 4 * j + 2] + sb2[4 * j + 2] + r4.z, 0.f);
    h[4 * j + 3] = fmaxf(agg[ln * 17 + 4 * j + 3] + sb2[4 * j + 3] + r4.w, 0.f);
  }
  // q=0/1 -> t3 rows q*4..+3 (W3_rel); q=2/3 -> r3 rows (q-2)*4..+3 (W3_root)
  const float* W = (q < 2) ? sW3rel : sW3root;
  int row0 = (q & 1) * 4;
  float o[4];
#pragma unroll
  for (int j = 0; j < 4; j++) {
    float acc = 0.f;
#pragma unroll
    for (int k = 0; k < 16; k++) acc += W[16 * (row0 + j) + k] * h[k];
    o[j] = acc;
  }
  if (q < 2) {
    __half2 p0 = __halves2half2(__float2half_rn(o[0]), __float2half_rn(o[1]));
    __half2 p1 = __halves2half2(__float2half_rn(o[2]), __float2half_rn(o[3]));
    *(uint2*)&t3h[(size_t)node * 4 + q * 2] = make_uint2(*(unsigned*)&p0, *(unsigned*)&p1);
  } else {
    *(float4*)&r3[(size_t)node * 8 + row0] = make_float4(o[0], o[1], o[2], o[3]);
  }
}

// ---------- layer 3: 4-wide 16B gather, fused relu + pooled max ----------
__global__ __launch_bounds__(256) void layer3_kernel(
    const unsigned* __restrict__ packed, const unsigned* __restrict__ bucketStart,
    const unsigned* __restrict__ bucketTotal,
    const uint4* __restrict__ t3h4, const float* __restrict__ r3,
    const float* __restrict__ b3,
    const int* __restrict__ batch, unsigned* __restrict__ pooled) {
  __shared__ float agg[65 * 9];
  __shared__ float sb3[8];
  for (int i = threadIdx.x; i < 65 * 9; i += 256) agg[i] = 0.f;
  if (threadIdx.x < 8) sb3[threadIdx.x] = b3[threadIdx.x];
  __syncthreads();
  int blk = blockIdx.x;
  unsigned e0 = bucketStart[blk];
  unsigned n = (bucketTotal[blk] + 3u) & ~3u;
  for (unsigned base = threadIdx.x * 4; base < n; base += 1024) {
    uint4 pk = *(const uint4*)&packed[e0 + base];
    uint4 g0 = t3h4[pk.x >> 7], g1 = t3h4[pk.y >> 7];
    uint4 g2 = t3h4[pk.z >> 7], g3 = t3h4[pk.w >> 7];
    unsigned dls[4] = {pk.x & 127u, pk.y & 127u, pk.z & 127u, pk.w & 127u};
    uint4 gs[4] = {g0, g1, g2, g3};
#pragma unroll
    for (int e = 0; e < 4; e++) {
      int a = (int)dls[e] * 9;
      float f[8];
      half8_unpack(gs[e], f);
#pragma unroll
      for (int j = 0; j < 8; j++) atomicAdd(&agg[a + j], f[j]);
    }
  }
  __syncthreads();
  int t = threadIdx.x;
  if (t < 128) {
    int ln = t >> 1, half = t & 1;
    int node = blk * 64 + ln;
    int g = batch[node];
    float4 r = *(const float4*)&r3[(size_t)node * 8 + half * 4];
    float rr[4] = {r.x, r.y, r.z, r.w};
#pragma unroll
    for (int f = 0; f < 4; f++) {
      int fi = half * 4 + f;
      float h = fmaxf(agg[ln * 9 + fi] + sb3[fi] + rr[f], 0.f);
      atomicMax(&pooled[8 * g + fi], __float_as_uint(h));  // relu>=0: uint order==float order
    }
  }
}

__global__ __launch_bounds__(256) void final_kernel(
    const unsigned* __restrict__ pooled, const float* __restrict__ W_lin,
    const float* __restrict__ b_lin, float* __restrict__ out) {
  int g = blockIdx.x * blockDim.x + threadIdx.x;
  if (g >= N_GRAPHS) return;
  float acc = b_lin[0];
#pragma unroll
  for (int f = 0; f < 8; f++) acc += __uint_as_float(pooled[8 * g + f]) * W_lin[f];
  out[g] = acc;
}

extern "C" void kernel_launch(void* const* d_in, const int* in_sizes, int n_in,
                              void* d_out, int out_size, void* d_ws, size_t ws_size,
                              hipStream_t stream) {
  const float* x = (const float*)d_in[0];
  const int* ei = (const int*)d_in[1];
  const int* src = ei;
  const int* dst = ei + N_EDGES;
  const int* batch = (const int*)d_in[2];
  const float* W1_rel = (const float*)d_in[3];
  const float* b1 = (const float*)d_in[4];
  const float* W1_root = (const float*)d_in[5];
  const float* W2_rel = (const float*)d_in[6];
  const float* b2 = (const float*)d_in[7];
  const float* W2_root = (const float*)d_in[8];
  const float* W3_rel = (const float*)d_in[9];
  const float* b3 = (const float*)d_in[10];
  const float* W3_root = (const float*)d_in[11];
  const float* W_lin = (const float*)d_in[12];
  const float* b_lin = (const float*)d_in[13];
  float* out = (float*)d_out;

  // ---- workspace layout (bytes), total < 58 MB ----
  char* ws = (char*)d_ws;
  unsigned* packed = (unsigned*)(ws + 0);                 // 25,640,000 (6.41M edges incl pads)
  unsigned short* H = (unsigned short*)(ws + 25640000);   // 19,531,250 — dead before layer1
  unsigned* t2h = (unsigned*)(ws + 25640000);             // 6,400,000 (fp16 x16, interleaved 32B)
  float* r2 = (float*)(ws + 32040000);                    // 12,800,000
  unsigned* t3h = (unsigned*)(ws + 44840000);             // 3,200,000 (fp16 x8, 16B)
  float* r3 = (float*)(ws + 48040000);                    // 6,400,000
  float4* xpad = (float4*)(ws + 54440000);                // 3,200,000
  unsigned* pooled = (unsigned*)(ws + 57640000);          // 16,384
  unsigned* bucketTotal = (unsigned*)(ws + 57656384);     // 12,500
  unsigned* bucketStart = (unsigned*)(ws + 57668884);     // 12,500
  unsigned* P = (unsigned*)(ws + 57681384);               // 312,500 -> end 57,993,884

  hipMemsetAsync(pooled, 0, N_GRAPHS * 8 * sizeof(unsigned), stream);

  xpad_kernel<<<(N_NODES + 255) / 256, 256, 0, stream>>>(x, xpad);
  count_kernel<<<NCH, 256, 0, stream>>>(dst, H);
  scan_bins1_kernel<<<dim3((NB + 255) / 256, NGRP), 256, 0, stream>>>(H, P);
  scan_bins2_kernel<<<(NB + 255) / 256, 256, 0, stream>>>(P, bucketTotal);
  scan_total_kernel<<<1, 256, 0, stream>>>(bucketTotal, bucketStart);
  pad_fill_kernel<<<(NB + 255) / 256, 256, 0, stream>>>(bucketStart, bucketTotal, packed);
  scatter_sorted_kernel<<<NCH, 256, 0, stream>>>(src, dst, H, P, bucketStart, packed);

  layer1_kernel<<<NB, 256, 0, stream>>>(packed, bucketStart, bucketTotal, xpad,
                                        W1_rel, b1, W1_root, W2_rel, W2_root, t2h, r2);
  layer2_kernel<<<NB, 256, 0, stream>>>(packed, bucketStart, bucketTotal,
                                        (const uint4*)t2h, r2, b2, W3_rel, W3_root, t3h, r3);
  layer3_kernel<<<NB, 256, 0, stream>>>(packed, bucketStart, bucketTotal,
                                        (const uint4*)t3h, r3, b3, batch, pooled);
  final_kernel<<<(N_GRAPHS + 255) / 256, 256, 0, stream>>>(pooled, W_lin, b_lin, out);
}

// Round 6
// 568.310 us; speedup vs baseline: 6.9636x; 2.3059x over previous
//
#include <hip/hip_runtime.h>
#include <hip/hip_fp16.h>

#define N_NODES 200000
#define N_EDGES 6400000
#define N_GRAPHS 512

#define NB 3125      // 64-node dst buckets: 3125*64 = 200000 exactly
#define NCH 3125     // edge chunks: 3125*2048 = 6,400,000 exactly
#define CHUNK 2048
#define NGRP 25      // chunk groups for parallel scan
#define CPG 125      // chunks per group
#define SEG 13       // 256*13 = 3328 >= NB
#define SCAP 3072    // max edges per bucket (mean 2048, sd ~45: +22 sigma)

// ---------- partition pass 1: counting sort of edges by dst>>6 ----------
// H (ushort) TRANSPOSED: H[c*NB + b]

__global__ __launch_bounds__(256) void count_kernel(const int* __restrict__ dst,
                                                    unsigned short* __restrict__ H) {
  __shared__ unsigned hist[NB];
  for (int i = threadIdx.x; i < NB; i += 256) hist[i] = 0;
  __syncthreads();
  int c = blockIdx.x;
  long e0 = (long)c * CHUNK;
  for (int i = threadIdx.x; i < CHUNK; i += 256) atomicAdd(&hist[dst[e0 + i] >> 6], 1u);
  __syncthreads();
  for (int i = threadIdx.x; i < NB; i += 256) H[(size_t)c * NB + i] = (unsigned short)hist[i];
}

__global__ __launch_bounds__(256) void scan_bins1_kernel(unsigned short* __restrict__ H,
                                                         unsigned* __restrict__ P) {
  int b = blockIdx.x * 256 + threadIdx.x;
  int g = blockIdx.y;
  if (b >= NB) return;
  unsigned run = 0;
  for (int c = g * CPG; c < (g + 1) * CPG; c++) {
    unsigned t = H[(size_t)c * NB + b];
    H[(size_t)c * NB + b] = (unsigned short)run;
    run += t;
  }
  P[(size_t)g * NB + b] = run;
}

__global__ __launch_bounds__(256) void scan_bins2_kernel(unsigned* __restrict__ P,
                                                         unsigned* __restrict__ bucketTotal) {
  int b = blockIdx.x * 256 + threadIdx.x;
  if (b >= NB) return;
  unsigned run = 0;
  for (int g = 0; g < NGRP; g++) {
    unsigned t = P[(size_t)g * NB + b];
    P[(size_t)g * NB + b] = run;
    run += t;
  }
  bucketTotal[b] = run;
}

// exclusive scan of totals -> bucketStart[NB+1] (one block)
__global__ __launch_bounds__(256) void scan_total_kernel(const unsigned* __restrict__ bucketTotal,
                                                         unsigned* __restrict__ bucketStart) {
  __shared__ unsigned sv[256 * SEG];
  __shared__ unsigned partial[256];
  int t = threadIdx.x;
  for (int i = t; i < 256 * SEG; i += 256) sv[i] = (i < NB) ? bucketTotal[i] : 0u;
  __syncthreads();
  unsigned sum = 0;
#pragma unroll
  for (int k = 0; k < SEG; k++) sum += sv[t * SEG + k];
  partial[t] = sum;
  __syncthreads();
  for (int off = 1; off < 256; off <<= 1) {
    unsigned add = (t >= off) ? partial[t - off] : 0u;
    __syncthreads();
    partial[t] += add;
    __syncthreads();
  }
  unsigned run = partial[t] - sum;
#pragma unroll
  for (int k = 0; k < SEG; k++) {
    unsigned w = sv[t * SEG + k];
    sv[t * SEG + k] = run;
    run += w;
  }
  __syncthreads();
  for (int i = t; i < NB; i += 256) bucketStart[i] = sv[i];
  if (t == 0) bucketStart[NB] = N_EDGES;
}

// chunk-local LDS counting sort by bucket, coalesced-run writes -> packedA = (src<<7)|dl
__global__ __launch_bounds__(256) void scatter_sorted_kernel(
    const int* __restrict__ src, const int* __restrict__ dst,
    const unsigned short* __restrict__ H, const unsigned* __restrict__ P,
    const unsigned* __restrict__ bucketStart, unsigned* __restrict__ packed) {
  __shared__ unsigned ssort[CHUNK];
  __shared__ unsigned short sbort[CHUNK];
  __shared__ unsigned hist[3328];
  __shared__ unsigned cur[3328];
  __shared__ unsigned partial[256];
  int t = threadIdx.x;
  int c = blockIdx.x;
  int g = c / CPG;
  long e0 = (long)c * CHUNK;
  for (int i = t; i < 3328; i += 256) hist[i] = 0;
  __syncthreads();
  for (int i = t; i < CHUNK; i += 256) atomicAdd(&hist[dst[e0 + i] >> 6], 1u);
  __syncthreads();
  unsigned a[SEG], sum = 0;
#pragma unroll
  for (int k = 0; k < SEG; k++) { a[k] = hist[SEG * t + k]; sum += a[k]; }
  partial[t] = sum;
  __syncthreads();
  for (int off = 1; off < 256; off <<= 1) {
    unsigned add = (t >= off) ? partial[t - off] : 0u;
    __syncthreads();
    partial[t] += add;
    __syncthreads();
  }
  unsigned run = partial[t] - sum;
#pragma unroll
  for (int k = 0; k < SEG; k++) {
    hist[SEG * t + k] = run;
    cur[SEG * t + k] = run;
    run += a[k];
  }
  __syncthreads();
  for (int i = t; i < CHUNK; i += 256) {
    int d = dst[e0 + i], s = src[e0 + i];
    int b = d >> 6;
    unsigned r = atomicAdd(&cur[b], 1u);
    ssort[r] = ((unsigned)s << 7) | (unsigned)(d & 63);
    sbort[r] = (unsigned short)b;
  }
  __syncthreads();
  for (int b = t; b < NB; b += 256)
    cur[b] = bucketStart[b] + P[(size_t)g * NB + b] + H[(size_t)c * NB + b] - hist[b];
  __syncthreads();
  for (int j = t; j < CHUNK; j += 256) packed[cur[sbort[j]] + j] = ssort[j];
}

// ---------- partition pass 2: within-bucket sort by node -> full CSR ----------
__global__ __launch_bounds__(256) void sort2_kernel(const unsigned* __restrict__ packedA,
                                                    const unsigned* __restrict__ bucketStart,
                                                    unsigned* __restrict__ packedB,
                                                    unsigned* __restrict__ nodeStart) {
  __shared__ unsigned buf[SCAP];
  __shared__ unsigned buf2[SCAP];
  __shared__ unsigned hist[64], base[64], cur[64];
  int t = threadIdx.x, b = blockIdx.x;
  unsigned s0 = bucketStart[b], s1 = bucketStart[b + 1];
  int n = (int)(s1 - s0);
  if (t < 64) hist[t] = 0;
  for (int i = t; i < n; i += 256) buf[i] = packedA[s0 + i];
  __syncthreads();
  for (int i = t; i < n; i += 256) atomicAdd(&hist[buf[i] & 63u], 1u);
  __syncthreads();
  if (t == 0) {
    unsigned run = 0;
    for (int k = 0; k < 64; k++) {
      unsigned v = hist[k];
      base[k] = run;
      cur[k] = run;
      run += v;
    }
  }
  __syncthreads();
  if (t < 64) nodeStart[b * 64 + t] = s0 + base[t];
  for (int i = t; i < n; i += 256) {
    unsigned p = buf[i];
    unsigned pos = atomicAdd(&cur[p & 63u], 1u);
    buf2[pos] = p >> 7;  // store src only; node implied by CSR position
  }
  __syncthreads();
  for (int i = t; i < n; i += 256) packedB[s0 + i] = buf2[i];
  if (b == NB - 1 && t == 0) nodeStart[N_NODES] = N_EDGES;
}

// ---------- xpad ----------
__global__ __launch_bounds__(256) void xpad_kernel(const float* __restrict__ x,
                                                   float4* __restrict__ xp) {
  int n = blockIdx.x * 256 + threadIdx.x;
  if (n >= N_NODES) return;
  xp[n] = make_float4(x[3 * n], x[3 * n + 1], x[3 * n + 2], 0.f);
}

__device__ __forceinline__ void half8_unpack(uint4 g, float* f) {
  const __half2* h2 = reinterpret_cast<const __half2*>(&g);
#pragma unroll
  for (int j = 0; j < 4; j++) {
    float2 fj = __half22float2(h2[j]);
    f[2 * j] = fj.x;
    f[2 * j + 1] = fj.y;
  }
}

// ---------- layer 1: CSR register-accumulate x, fused transform ----------
__global__ __launch_bounds__(256) void layer1_kernel(
    const unsigned* __restrict__ packed, const unsigned* __restrict__ nodeStart,
    const float4* __restrict__ xp,
    const float* __restrict__ W1_rel, const float* __restrict__ b1,
    const float* __restrict__ W1_root,
    const float* __restrict__ W2_rel, const float* __restrict__ W2_root,
    unsigned* __restrict__ t2h, float* __restrict__ r2) {
  __shared__ float sW1rel[96], sW1root[96], sb1[32], sW2rel[512], sW2root[512];
  __shared__ float plds[256 * 4];
  for (int i = threadIdx.x; i < 96; i += 256) { sW1rel[i] = W1_rel[i]; sW1root[i] = W1_root[i]; }
  for (int i = threadIdx.x; i < 32; i += 256) sb1[i] = b1[i];
  for (int i = threadIdx.x; i < 512; i += 256) { sW2rel[i] = W2_rel[i]; sW2root[i] = W2_root[i]; }
  __syncthreads();
  int t = threadIdx.x, ln = t >> 2, part = t & 3;
  int node = blockIdx.x * 64 + ln;
  unsigned sB = nodeStart[node + 1];
  unsigned i = nodeStart[node] + part;
  float a0 = 0.f, a1 = 0.f, a2 = 0.f;
  unsigned scur = (i < sB) ? packed[i] : 0u;
  while (i < sB) {
    unsigned inext = i + 4;
    unsigned snext = (inext < sB) ? packed[inext] : 0u;
    float4 v = xp[scur];
    a0 += v.x; a1 += v.y; a2 += v.z;
    i = inext; scur = snext;
  }
  plds[t * 4] = a0; plds[t * 4 + 1] = a1; plds[t * 4 + 2] = a2;
  __syncthreads();
  int pb = ln * 16;
  float A0 = plds[pb] + plds[pb + 4] + plds[pb + 8] + plds[pb + 12];
  float A1 = plds[pb + 1] + plds[pb + 5] + plds[pb + 9] + plds[pb + 13];
  float A2 = plds[pb + 2] + plds[pb + 6] + plds[pb + 10] + plds[pb + 14];
  float4 xv = xp[node];
  float h[32];
#pragma unroll
  for (int k = 0; k < 32; k++) {
    float v = sW1rel[3 * k] * A0 + sW1rel[3 * k + 1] * A1 + sW1rel[3 * k + 2] * A2 +
              sW1root[3 * k] * xv.x + sW1root[3 * k + 1] * xv.y + sW1root[3 * k + 2] * xv.z +
              sb1[k];
    h[k] = fmaxf(v, 0.f);
  }
  int jb = part * 4;
  float tv[4], rv[4];
#pragma unroll
  for (int j = 0; j < 4; j++) {
    float acc = 0.f, accr = 0.f;
#pragma unroll
    for (int k = 0; k < 32; k++) {
      acc += sW2rel[32 * (jb + j) + k] * h[k];
      accr += sW2root[32 * (jb + j) + k] * h[k];
    }
    tv[j] = acc;
    rv[j] = accr;
  }
  __half2 p0 = __halves2half2(__float2half_rn(tv[0]), __float2half_rn(tv[1]));
  __half2 p1 = __halves2half2(__float2half_rn(tv[2]), __float2half_rn(tv[3]));
  *(uint2*)&t2h[(size_t)node * 8 + part * 2] = make_uint2(*(unsigned*)&p0, *(unsigned*)&p1);
  *(float4*)&r2[(size_t)node * 16 + jb] = make_float4(rv[0], rv[1], rv[2], rv[3]);
}

// ---------- layer 2: CSR register-accumulate 16 fp16 feats, fused transform ----------
__global__ __launch_bounds__(256) void layer2_kernel(
    const unsigned* __restrict__ packed, const unsigned* __restrict__ nodeStart,
    const uint4* __restrict__ t2h4, const float* __restrict__ r2,
    const float* __restrict__ b2,
    const float* __restrict__ W3_rel, const float* __restrict__ W3_root,
    unsigned* __restrict__ t3h, float* __restrict__ r3) {
  __shared__ float sW3rel[128], sW3root[128], sb2[16];
  __shared__ float plds[256 * 16];  // 16 KB partials
  for (int i = threadIdx.x; i < 128; i += 256) { sW3rel[i] = W3_rel[i]; sW3root[i] = W3_root[i]; }
  if (threadIdx.x < 16) sb2[threadIdx.x] = b2[threadIdx.x];
  __syncthreads();
  int t = threadIdx.x, ln = t >> 2, part = t & 3;
  int node = blockIdx.x * 64 + ln;
  unsigned sB = nodeStart[node + 1];
  unsigned i = nodeStart[node] + part;
  float acc[16];
#pragma unroll
  for (int j = 0; j < 16; j++) acc[j] = 0.f;
  unsigned scur = (i < sB) ? packed[i] : 0u;
  while (i < sB) {
    unsigned inext = i + 4;
    unsigned snext = (inext < sB) ? packed[inext] : 0u;
    uint4 ga = t2h4[(size_t)scur * 2];
    uint4 gb = t2h4[(size_t)scur * 2 + 1];
    float f[8];
    half8_unpack(ga, f);
#pragma unroll
    for (int j = 0; j < 8; j++) acc[j] += f[j];
    half8_unpack(gb, f);
#pragma unroll
    for (int j = 0; j < 8; j++) acc[8 + j] += f[j];
    i = inext; scur = snext;
  }
#pragma unroll
  for (int j = 0; j < 16; j++) plds[t * 16 + j] = acc[j];
  __syncthreads();
  int pb = ln * 64;
  float h[16];
#pragma unroll
  for (int j = 0; j < 16; j++)
    h[j] = plds[pb + j] + plds[pb + 16 + j] + plds[pb + 32 + j] + plds[pb + 48 + j];
  const float4* rr = (const float4*)&r2[(size_t)node * 16];
#pragma unroll
  for (int j = 0; j < 4; j++) {
    float4 r4 = rr[j];
    h[4 * j + 0] = fmaxf(h[4 * j + 0] + sb2[4 * j + 0] + r4.x, 0.f);
    h[4 * j + 1] = fmaxf(h[4 * j + 1] + sb2[4 * j + 1] + r4.y, 0.f);
    h[4 * j + 2] = fmaxf(h[4 * j + 2] + sb2[4 * j + 2] + r4.z, 0.f);
    h[4 * j + 3] = fmaxf(h[4 * j + 3] + sb2[4 * j + 3] + r4.w, 0.f);
  }
  // part 0/1 -> t3 rows (part&1)*4.. (W3_rel); part 2/3 -> r3 rows (W3_root)
  const float* W = (part < 2) ? sW3rel : sW3root;
  int row0 = (part & 1) * 4;
  float o[4];
#pragma unroll
  for (int j = 0; j < 4; j++) {
    float a3 = 0.f;
#pragma unroll
    for (int k = 0; k < 16; k++) a3 += W[16 * (row0 + j) + k] * h[k];
    o[j] = a3;
  }
  if (part < 2) {
    __half2 p0 = __halves2half2(__float2half_rn(o[0]), __float2half_rn(o[1]));
    __half2 p1 = __halves2half2(__float2half_rn(o[2]), __float2half_rn(o[3]));
    *(uint2*)&t3h[(size_t)node * 4 + part * 2] = make_uint2(*(unsigned*)&p0, *(unsigned*)&p1);
  } else {
    *(float4*)&r3[(size_t)node * 8 + row0] = make_float4(o[0], o[1], o[2], o[3]);
  }
}

// ---------- layer 3: CSR register-accumulate 8 fp16 feats, fused relu + pool ----------
__global__ __launch_bounds__(256) void layer3_kernel(
    const unsigned* __restrict__ packed, const unsigned* __restrict__ nodeStart,
    const uint4* __restrict__ t3h4, const float* __restrict__ r3,
    const float* __restrict__ b3,
    const int* __restrict__ batch, unsigned* __restrict__ pooled) {
  __shared__ float plds[256 * 8];
  __shared__ float sb3[8];
  if (threadIdx.x < 8) sb3[threadIdx.x] = b3[threadIdx.x];
  __syncthreads();
  int t = threadIdx.x, ln = t >> 2, part = t & 3;
  int node = blockIdx.x * 64 + ln;
  unsigned sB = nodeStart[node + 1];
  unsigned i = nodeStart[node] + part;
  float acc[8];
#pragma unroll
  for (int j = 0; j < 8; j++) acc[j] = 0.f;
  unsigned scur = (i < sB) ? packed[i] : 0u;
  while (i < sB) {
    unsigned inext = i + 4;
    unsigned snext = (inext < sB) ? packed[inext] : 0u;
    uint4 g = t3h4[scur];
    float f[8];
    half8_unpack(g, f);
#pragma unroll
    for (int j = 0; j < 8; j++) acc[j] += f[j];
    i = inext; scur = snext;
  }
#pragma unroll
  for (int j = 0; j < 8; j++) plds[t * 8 + j] = acc[j];
  __syncthreads();
  int g = batch[node];
  int pb = ln * 32;
#pragma unroll
  for (int k = 0; k < 2; k++) {
    int fi = part * 2 + k;
    float v = plds[pb + fi] + plds[pb + 8 + fi] + plds[pb + 16 + fi] + plds[pb + 24 + fi];
    float h = fmaxf(v + sb3[fi] + r3[(size_t)node * 8 + fi], 0.f);
    atomicMax(&pooled[8 * g + fi], __float_as_uint(h));  // relu>=0: uint order==float order
  }
}

__global__ __launch_bounds__(256) void final_kernel(
    const unsigned* __restrict__ pooled, const float* __restrict__ W_lin,
    const float* __restrict__ b_lin, float* __restrict__ out) {
  int g = blockIdx.x * blockDim.x + threadIdx.x;
  if (g >= N_GRAPHS) return;
  float acc = b_lin[0];
#pragma unroll
  for (int f = 0; f < 8; f++) acc += __uint_as_float(pooled[8 * g + f]) * W_lin[f];
  out[g] = acc;
}

extern "C" void kernel_launch(void* const* d_in, const int* in_sizes, int n_in,
                              void* d_out, int out_size, void* d_ws, size_t ws_size,
                              hipStream_t stream) {
  const float* x = (const float*)d_in[0];
  const int* ei = (const int*)d_in[1];
  const int* src = ei;
  const int* dst = ei + N_EDGES;
  const int* batch = (const int*)d_in[2];
  const float* W1_rel = (const float*)d_in[3];
  const float* b1 = (const float*)d_in[4];
  const float* W1_root = (const float*)d_in[5];
  const float* W2_rel = (const float*)d_in[6];
  const float* b2 = (const float*)d_in[7];
  const float* W2_root = (const float*)d_in[8];
  const float* W3_rel = (const float*)d_in[9];
  const float* b3 = (const float*)d_in[10];
  const float* W3_root = (const float*)d_in[11];
  const float* W_lin = (const float*)d_in[12];
  const float* b_lin = (const float*)d_in[13];
  float* out = (float*)d_out;

  // ---- workspace layout (bytes) ----
  // region0 [0, 25.6M): packedA during partition; after sort2 reused for r2|r3|t3h|xpad
  // region1 [25.6M, 51.2M): H (ushort) during partition; packedB (CSR src) after
  // region2 [51.2M, 57.6M): t2h
  char* ws = (char*)d_ws;
  unsigned* packedA = (unsigned*)(ws + 0);                // 25,600,000
  float* r2 = (float*)(ws + 0);                           // 12,800,000 (alias, post-sort2)
  float* r3 = (float*)(ws + 12800000);                    // 6,400,000
  unsigned* t3h = (unsigned*)(ws + 19200000);             // 3,200,000
  float4* xpad = (float4*)(ws + 22400000);                // 3,200,000
  unsigned short* H = (unsigned short*)(ws + 25600000);   // 19,531,250 (dead before packedB)
  unsigned* packedB = (unsigned*)(ws + 25600000);         // 25,600,000 (CSR src indices)
  unsigned* t2h = (unsigned*)(ws + 51200000);             // 6,400,000
  unsigned* pooled = (unsigned*)(ws + 57600000);          // 16,384
  unsigned* bucketStart = (unsigned*)(ws + 57616384);     // 12,504 (NB+1)
  unsigned* bucketTotal = (unsigned*)(ws + 57628888);     // 12,500
  unsigned* P = (unsigned*)(ws + 57641388);               // 312,500
  unsigned* nodeStart = (unsigned*)(ws + 57953888);       // 800,004 -> end 58,753,892 (<60.0MB known-ok)

  hipMemsetAsync(pooled, 0, N_GRAPHS * 8 * sizeof(unsigned), stream);

  // partition: two-level counting sort to full dst-CSR
  count_kernel<<<NCH, 256, 0, stream>>>(dst, H);
  scan_bins1_kernel<<<dim3((NB + 255) / 256, NGRP), 256, 0, stream>>>(H, P);
  scan_bins2_kernel<<<(NB + 255) / 256, 256, 0, stream>>>(P, bucketTotal);
  scan_total_kernel<<<1, 256, 0, stream>>>(bucketTotal, bucketStart);
  scatter_sorted_kernel<<<NCH, 256, 0, stream>>>(src, dst, H, P, bucketStart, packedA);
  sort2_kernel<<<NB, 256, 0, stream>>>(packedA, bucketStart, packedB, nodeStart);
  xpad_kernel<<<(N_NODES + 255) / 256, 256, 0, stream>>>(x, xpad);  // after sort2: aliases packedA

  // layers: atomic-free register accumulation over CSR runs
  layer1_kernel<<<NB, 256, 0, stream>>>(packedB, nodeStart, xpad,
                                        W1_rel, b1, W1_root, W2_rel, W2_root, t2h, r2);
  layer2_kernel<<<NB, 256, 0, stream>>>(packedB, nodeStart, (const uint4*)t2h, r2, b2,
                                        W3_rel, W3_root, t3h, r3);
  layer3_kernel<<<NB, 256, 0, stream>>>(packedB, nodeStart, (const uint4*)t3h, r3, b3,
                                        batch, pooled);
  final_kernel<<<(N_GRAPHS + 255) / 256, 256, 0, stream>>>(pooled, W_lin, b_lin, out);
}

// Round 7
// 556.219 us; speedup vs baseline: 7.1150x; 1.0217x over previous
//
#include <hip/hip_runtime.h>
#include <hip/hip_fp16.h>

#define N_NODES 200000
#define N_EDGES 6400000
#define N_GRAPHS 512

#define NB 3125      // 64-node dst buckets: 3125*64 = 200000 exactly
#define NCH 3125     // edge chunks: 3125*2048 = 6,400,000 exactly
#define CHUNK 2048
#define NGRP 25      // chunk groups for parallel scan
#define CPG 125      // chunks per group
#define SEG 13       // 256*13 = 3328 >= NB
#define SCAP 3072    // max edges per bucket (mean 2048, sd ~45)

// ---------- non-temporal helpers ----------
typedef float vf4 __attribute__((ext_vector_type(4)));
typedef unsigned vu4 __attribute__((ext_vector_type(4)));
typedef float vf2 __attribute__((ext_vector_type(2)));
typedef unsigned vu2 __attribute__((ext_vector_type(2)));

__device__ __forceinline__ unsigned ntload_u(const unsigned* p) {
  return __builtin_nontemporal_load(p);
}
__device__ __forceinline__ int ntload_i(const int* p) { return __builtin_nontemporal_load(p); }
__device__ __forceinline__ float ntload_f(const float* p) {
  return __builtin_nontemporal_load(p);
}
__device__ __forceinline__ float2 ntload_f2(const float* p) {
  vf2 v = __builtin_nontemporal_load((const vf2*)p);
  return make_float2(v.x, v.y);
}
__device__ __forceinline__ void ntstore_u2(unsigned* p, uint2 v) {
  vu2 t = {v.x, v.y};
  __builtin_nontemporal_store(t, (vu2*)p);
}
__device__ __forceinline__ void ntstore_f2(float* p, float2 v) {
  vf2 t = {v.x, v.y};
  __builtin_nontemporal_store(t, (vf2*)p);
}
__device__ __forceinline__ void ntstore_f4(float* p, float4 v) {
  vf4 t = {v.x, v.y, v.z, v.w};
  __builtin_nontemporal_store(t, (vf4*)p);
}
__device__ __forceinline__ void ntstore_u(unsigned* p, unsigned v) {
  __builtin_nontemporal_store(v, p);
}

// ---------- partition pass 1: counting sort of edges by dst>>6 ----------
// H (ushort) TRANSPOSED: H[c*NB + b]

__global__ __launch_bounds__(256) void count_kernel(const int* __restrict__ dst,
                                                    unsigned short* __restrict__ H) {
  __shared__ unsigned hist[NB];
  for (int i = threadIdx.x; i < NB; i += 256) hist[i] = 0;
  __syncthreads();
  int c = blockIdx.x;
  long e0 = (long)c * CHUNK;
  for (int i = threadIdx.x; i < CHUNK; i += 256) atomicAdd(&hist[dst[e0 + i] >> 6], 1u);
  __syncthreads();
  for (int i = threadIdx.x; i < NB; i += 256) H[(size_t)c * NB + i] = (unsigned short)hist[i];
}

__global__ __launch_bounds__(256) void scan_bins1_kernel(unsigned short* __restrict__ H,
                                                         unsigned* __restrict__ P) {
  int b = blockIdx.x * 256 + threadIdx.x;
  int g = blockIdx.y;
  if (b >= NB) return;
  unsigned run = 0;
  for (int c = g * CPG; c < (g + 1) * CPG; c++) {
    unsigned t = H[(size_t)c * NB + b];
    H[(size_t)c * NB + b] = (unsigned short)run;
    run += t;
  }
  P[(size_t)g * NB + b] = run;
}

__global__ __launch_bounds__(256) void scan_bins2_kernel(unsigned* __restrict__ P,
                                                         unsigned* __restrict__ bucketTotal) {
  int b = blockIdx.x * 256 + threadIdx.x;
  if (b >= NB) return;
  unsigned run = 0;
  for (int g = 0; g < NGRP; g++) {
    unsigned t = P[(size_t)g * NB + b];
    P[(size_t)g * NB + b] = run;
    run += t;
  }
  bucketTotal[b] = run;
}

// exclusive scan of totals -> bucketStart[NB+1] (one block)
__global__ __launch_bounds__(256) void scan_total_kernel(const unsigned* __restrict__ bucketTotal,
                                                         unsigned* __restrict__ bucketStart) {
  __shared__ unsigned sv[256 * SEG];
  __shared__ unsigned partial[256];
  int t = threadIdx.x;
  for (int i = t; i < 256 * SEG; i += 256) sv[i] = (i < NB) ? bucketTotal[i] : 0u;
  __syncthreads();
  unsigned sum = 0;
#pragma unroll
  for (int k = 0; k < SEG; k++) sum += sv[t * SEG + k];
  partial[t] = sum;
  __syncthreads();
  for (int off = 1; off < 256; off <<= 1) {
    unsigned add = (t >= off) ? partial[t - off] : 0u;
    __syncthreads();
    partial[t] += add;
    __syncthreads();
  }
  unsigned run = partial[t] - sum;
#pragma unroll
  for (int k = 0; k < SEG; k++) {
    unsigned w = sv[t * SEG + k];
    sv[t * SEG + k] = run;
    run += w;
  }
  __syncthreads();
  for (int i = t; i < NB; i += 256) bucketStart[i] = sv[i];
  if (t == 0) bucketStart[NB] = N_EDGES;
}

// chunk-local LDS counting sort by bucket, coalesced-run writes -> packedA = (src<<7)|dl
__global__ __launch_bounds__(256) void scatter_sorted_kernel(
    const int* __restrict__ src, const int* __restrict__ dst,
    const unsigned short* __restrict__ H, const unsigned* __restrict__ P,
    const unsigned* __restrict__ bucketStart, unsigned* __restrict__ packed) {
  __shared__ unsigned ssort[CHUNK];
  __shared__ unsigned short sbort[CHUNK];
  __shared__ unsigned hist[3328];
  __shared__ unsigned cur[3328];
  __shared__ unsigned partial[256];
  int t = threadIdx.x;
  int c = blockIdx.x;
  int g = c / CPG;
  long e0 = (long)c * CHUNK;
  for (int i = t; i < 3328; i += 256) hist[i] = 0;
  __syncthreads();
  for (int i = t; i < CHUNK; i += 256) atomicAdd(&hist[dst[e0 + i] >> 6], 1u);
  __syncthreads();
  unsigned a[SEG], sum = 0;
#pragma unroll
  for (int k = 0; k < SEG; k++) { a[k] = hist[SEG * t + k]; sum += a[k]; }
  partial[t] = sum;
  __syncthreads();
  for (int off = 1; off < 256; off <<= 1) {
    unsigned add = (t >= off) ? partial[t - off] : 0u;
    __syncthreads();
    partial[t] += add;
    __syncthreads();
  }
  unsigned run = partial[t] - sum;
#pragma unroll
  for (int k = 0; k < SEG; k++) {
    hist[SEG * t + k] = run;
    cur[SEG * t + k] = run;
    run += a[k];
  }
  __syncthreads();
  for (int i = t; i < CHUNK; i += 256) {
    int d = dst[e0 + i], s = src[e0 + i];
    int b = d >> 6;
    unsigned r = atomicAdd(&cur[b], 1u);
    ssort[r] = ((unsigned)s << 7) | (unsigned)(d & 63);
    sbort[r] = (unsigned short)b;
  }
  __syncthreads();
  for (int b = t; b < NB; b += 256)
    cur[b] = bucketStart[b] + P[(size_t)g * NB + b] + H[(size_t)c * NB + b] - hist[b];
  __syncthreads();
  for (int j = t; j < CHUNK; j += 256) packed[cur[sbort[j]] + j] = ssort[j];
}

// ---------- partition pass 2: within-bucket sort by node -> full CSR ----------
__global__ __launch_bounds__(256) void sort2_kernel(const unsigned* __restrict__ packedA,
                                                    const unsigned* __restrict__ bucketStart,
                                                    unsigned* __restrict__ packedB,
                                                    unsigned* __restrict__ nodeStart) {
  __shared__ unsigned buf[SCAP];
  __shared__ unsigned buf2[SCAP];
  __shared__ unsigned hist[64], base[64], cur[64];
  int t = threadIdx.x, b = blockIdx.x;
  unsigned s0 = bucketStart[b], s1 = bucketStart[b + 1];
  int n = (int)(s1 - s0);
  if (t < 64) hist[t] = 0;
  for (int i = t; i < n; i += 256) buf[i] = packedA[s0 + i];
  __syncthreads();
  for (int i = t; i < n; i += 256) atomicAdd(&hist[buf[i] & 63u], 1u);
  __syncthreads();
  if (t == 0) {
    unsigned run = 0;
    for (int k = 0; k < 64; k++) {
      unsigned v = hist[k];
      base[k] = run;
      cur[k] = run;
      run += v;
    }
  }
  __syncthreads();
  if (t < 64) nodeStart[b * 64 + t] = s0 + base[t];
  for (int i = t; i < n; i += 256) {
    unsigned p = buf[i];
    unsigned pos = atomicAdd(&cur[p & 63u], 1u);
    buf2[pos] = p >> 7;  // store src only; node implied by CSR position
  }
  __syncthreads();
  for (int i = t; i < n; i += 256) packedB[s0 + i] = buf2[i];
  if (b == NB - 1 && t == 0) nodeStart[N_NODES] = N_EDGES;
}

// ---------- xpad ----------
__global__ __launch_bounds__(256) void xpad_kernel(const float* __restrict__ x,
                                                   float4* __restrict__ xp) {
  int n = blockIdx.x * 256 + threadIdx.x;
  if (n >= N_NODES) return;
  xp[n] = make_float4(x[3 * n], x[3 * n + 1], x[3 * n + 2], 0.f);
}

__device__ __forceinline__ void half8_unpack(uint4 g, float* f) {
  const __half2* h2 = reinterpret_cast<const __half2*>(&g);
#pragma unroll
  for (int j = 0; j < 4; j++) {
    float2 fj = __half22float2(h2[j]);
    f[2 * j] = fj.x;
    f[2 * j + 1] = fj.y;
  }
}

// ---------- layer 1: CSR reg-accumulate x (4 thr/node), fused transform ----------
__global__ __launch_bounds__(256) void layer1_kernel(
    const unsigned* __restrict__ packed, const unsigned* __restrict__ nodeStart,
    const float4* __restrict__ xp,
    const float* __restrict__ W1_rel, const float* __restrict__ b1,
    const float* __restrict__ W1_root,
    const float* __restrict__ W2_rel, const float* __restrict__ W2_root,
    unsigned* __restrict__ t2h, float* __restrict__ r2) {
  __shared__ float sW1rel[96], sW1root[96], sb1[32], sW2rel[512], sW2root[512];
  __shared__ float plds[256 * 4];
  for (int i = threadIdx.x; i < 96; i += 256) { sW1rel[i] = W1_rel[i]; sW1root[i] = W1_root[i]; }
  for (int i = threadIdx.x; i < 32; i += 256) sb1[i] = b1[i];
  for (int i = threadIdx.x; i < 512; i += 256) { sW2rel[i] = W2_rel[i]; sW2root[i] = W2_root[i]; }
  __syncthreads();
  int t = threadIdx.x, ln = t >> 2, part = t & 3;
  int node = blockIdx.x * 64 + ln;
  unsigned sB = ntload_u(&nodeStart[node + 1]);
  unsigned i = ntload_u(&nodeStart[node]) + part;
  float a0 = 0.f, a1 = 0.f, a2 = 0.f;
  unsigned scur = (i < sB) ? ntload_u(&packed[i]) : 0u;
  float4 g = xp[scur];  // scur=0 safe
  while (i < sB) {
    unsigned inext = i + 4;
    unsigned snext = (inext < sB) ? ntload_u(&packed[inext]) : 0u;
    float4 gn = xp[snext];
    a0 += g.x; a1 += g.y; a2 += g.z;
    g = gn; i = inext;
  }
  plds[t * 4] = a0; plds[t * 4 + 1] = a1; plds[t * 4 + 2] = a2;
  __syncthreads();
  int pb = ln * 16;
  float A0 = plds[pb] + plds[pb + 4] + plds[pb + 8] + plds[pb + 12];
  float A1 = plds[pb + 1] + plds[pb + 5] + plds[pb + 9] + plds[pb + 13];
  float A2 = plds[pb + 2] + plds[pb + 6] + plds[pb + 10] + plds[pb + 14];
  float4 xv = xp[node];
  float h[32];
#pragma unroll
  for (int k = 0; k < 32; k++) {
    float v = sW1rel[3 * k] * A0 + sW1rel[3 * k + 1] * A1 + sW1rel[3 * k + 2] * A2 +
              sW1root[3 * k] * xv.x + sW1root[3 * k + 1] * xv.y + sW1root[3 * k + 2] * xv.z +
              sb1[k];
    h[k] = fmaxf(v, 0.f);
  }
  int jb = part * 4;
  float tv[4], rv[4];
#pragma unroll
  for (int j = 0; j < 4; j++) {
    float acc = 0.f, accr = 0.f;
#pragma unroll
    for (int k = 0; k < 32; k++) {
      acc += sW2rel[32 * (jb + j) + k] * h[k];
      accr += sW2root[32 * (jb + j) + k] * h[k];
    }
    tv[j] = acc;
    rv[j] = accr;
  }
  __half2 p0 = __halves2half2(__float2half_rn(tv[0]), __float2half_rn(tv[1]));
  __half2 p1 = __halves2half2(__float2half_rn(tv[2]), __float2half_rn(tv[3]));
  ntstore_u2(&t2h[(size_t)node * 8 + part * 2], make_uint2(*(unsigned*)&p0, *(unsigned*)&p1));
  ntstore_f4(&r2[(size_t)node * 16 + jb], make_float4(rv[0], rv[1], rv[2], rv[3]));
}

// ---------- layer 2: 8 thr/node; pairs read adjacent 16B halves (32B/edge coalesced) ----------
__global__ __launch_bounds__(256) void layer2_kernel(
    const unsigned* __restrict__ packed, const unsigned* __restrict__ nodeStart,
    const uint4* __restrict__ t2h4, const float* __restrict__ r2,
    const float* __restrict__ b2,
    const float* __restrict__ W3_rel, const float* __restrict__ W3_root,
    unsigned* __restrict__ t3h, float* __restrict__ r3) {
  __shared__ float sW3rel[128], sW3root[128], sb2[16];
  __shared__ float plds[256 * 9];  // stride 9: conflict-free combine
  __shared__ float hlds[32 * 16];
  for (int i = threadIdx.x; i < 128; i += 256) { sW3rel[i] = W3_rel[i]; sW3root[i] = W3_root[i]; }
  if (threadIdx.x < 16) sb2[threadIdx.x] = b2[threadIdx.x];
  __syncthreads();
  int t = threadIdx.x, ln = t >> 3, p = t & 7;
  int node = blockIdx.x * 32 + ln;
  int half = p & 1;      // which 16B of the 32B record
  unsigned sB = ntload_u(&nodeStart[node + 1]);
  unsigned i = ntload_u(&nodeStart[node]) + (p >> 1);
  float acc[8];
#pragma unroll
  for (int j = 0; j < 8; j++) acc[j] = 0.f;
  unsigned scur = (i < sB) ? ntload_u(&packed[i]) : 0u;
  uint4 g = t2h4[(size_t)scur * 2 + half];
  while (i < sB) {
    unsigned inext = i + 4;
    unsigned snext = (inext < sB) ? ntload_u(&packed[inext]) : 0u;
    uint4 gn = t2h4[(size_t)snext * 2 + half];
    float f[8];
    half8_unpack(g, f);
#pragma unroll
    for (int j = 0; j < 8; j++) acc[j] += f[j];
    g = gn; i = inext;
  }
#pragma unroll
  for (int j = 0; j < 8; j++) plds[t * 9 + j] = acc[j];
  __syncthreads();
  // h: thread computes feats 2p, 2p+1
  {
    float2 rv = ntload_f2(&r2[(size_t)node * 16 + 2 * p]);
    float hv[2];
#pragma unroll
    for (int k2 = 0; k2 < 2; k2++) {
      int f = 2 * p + k2;
      int fh = f >> 3, fi = f & 7;
      int q0 = (ln * 8 + fh) * 9 + fi;
      float s = plds[q0] + plds[q0 + 18] + plds[q0 + 36] + plds[q0 + 54];
      hv[k2] = s + sb2[f] + (k2 == 0 ? rv.x : rv.y);
    }
    hlds[ln * 16 + 2 * p] = fmaxf(hv[0], 0.f);
    hlds[ln * 16 + 2 * p + 1] = fmaxf(hv[1], 0.f);
  }
  __syncthreads();
  // rows: p<4 -> W3_rel rows 2p,2p+1 (t3); p>=4 -> W3_root rows 2(p-4).. (r3)
  const float* W = (p < 4) ? sW3rel : sW3root;
  int rbase = (p < 4) ? 2 * p : 2 * (p - 4);
  float o0 = 0.f, o1 = 0.f;
#pragma unroll
  for (int k = 0; k < 16; k++) {
    float hv = hlds[ln * 16 + k];
    o0 += W[16 * rbase + k] * hv;
    o1 += W[16 * (rbase + 1) + k] * hv;
  }
  if (p < 4) {
    __half2 pk = __halves2half2(__float2half_rn(o0), __float2half_rn(o1));
    ntstore_u(&t3h[(size_t)node * 4 + p], *(unsigned*)&pk);
  } else {
    ntstore_f2(&r3[(size_t)node * 8 + rbase], make_float2(o0, o1));
  }
}

// ---------- layer 3: 8 thr/node, stride-8 full 16B records, fused relu + pool ----------
__global__ __launch_bounds__(256) void layer3_kernel(
    const unsigned* __restrict__ packed, const unsigned* __restrict__ nodeStart,
    const uint4* __restrict__ t3h4, const float* __restrict__ r3,
    const float* __restrict__ b3,
    const int* __restrict__ batch, unsigned* __restrict__ pooled) {
  __shared__ float plds[256 * 9];
  __shared__ float sb3[8];
  if (threadIdx.x < 8) sb3[threadIdx.x] = b3[threadIdx.x];
  __syncthreads();
  int t = threadIdx.x, ln = t >> 3, p = t & 7;
  int node = blockIdx.x * 32 + ln;
  unsigned sB = ntload_u(&nodeStart[node + 1]);
  unsigned i = ntload_u(&nodeStart[node]) + p;
  float acc[8];
#pragma unroll
  for (int j = 0; j < 8; j++) acc[j] = 0.f;
  unsigned scur = (i < sB) ? ntload_u(&packed[i]) : 0u;
  uint4 g = t3h4[scur];
  while (i < sB) {
    unsigned inext = i + 8;
    unsigned snext = (inext < sB) ? ntload_u(&packed[inext]) : 0u;
    uint4 gn = t3h4[snext];
    float f[8];
    half8_unpack(g, f);
#pragma unroll
    for (int j = 0; j < 8; j++) acc[j] += f[j];
    g = gn; i = inext;
  }
#pragma unroll
  for (int j = 0; j < 8; j++) plds[t * 9 + j] = acc[j];
  __syncthreads();
  int gg = ntload_i(&batch[node]);
  int q0 = ln * 72 + p;  // (ln*8+k)*9 + p, k=0..7
  float v = plds[q0] + plds[q0 + 9] + plds[q0 + 18] + plds[q0 + 27] +
            plds[q0 + 36] + plds[q0 + 45] + plds[q0 + 54] + plds[q0 + 63];
  float h = fmaxf(v + sb3[p] + ntload_f(&r3[(size_t)node * 8 + p]), 0.f);
  atomicMax(&pooled[8 * gg + p], __float_as_uint(h));  // relu>=0: uint order==float order
}

__global__ __launch_bounds__(256) void final_kernel(
    const unsigned* __restrict__ pooled, const float* __restrict__ W_lin,
    const float* __restrict__ b_lin, float* __restrict__ out) {
  int g = blockIdx.x * blockDim.x + threadIdx.x;
  if (g >= N_GRAPHS) return;
  float acc = b_lin[0];
#pragma unroll
  for (int f = 0; f < 8; f++) acc += __uint_as_float(pooled[8 * g + f]) * W_lin[f];
  out[g] = acc;
}

extern "C" void kernel_launch(void* const* d_in, const int* in_sizes, int n_in,
                              void* d_out, int out_size, void* d_ws, size_t ws_size,
                              hipStream_t stream) {
  const float* x = (const float*)d_in[0];
  const int* ei = (const int*)d_in[1];
  const int* src = ei;
  const int* dst = ei + N_EDGES;
  const int* batch = (const int*)d_in[2];
  const float* W1_rel = (const float*)d_in[3];
  const float* b1 = (const float*)d_in[4];
  const float* W1_root = (const float*)d_in[5];
  const float* W2_rel = (const float*)d_in[6];
  const float* b2 = (const float*)d_in[7];
  const float* W2_root = (const float*)d_in[8];
  const float* W3_rel = (const float*)d_in[9];
  const float* b3 = (const float*)d_in[10];
  const float* W3_root = (const float*)d_in[11];
  const float* W_lin = (const float*)d_in[12];
  const float* b_lin = (const float*)d_in[13];
  float* out = (float*)d_out;

  // ---- workspace layout (bytes), same as R6 ----
  char* ws = (char*)d_ws;
  unsigned* packedA = (unsigned*)(ws + 0);                // 25,600,000
  float* r2 = (float*)(ws + 0);                           // 12,800,000 (alias, post-sort2)
  float* r3 = (float*)(ws + 12800000);                    // 6,400,000
  unsigned* t3h = (unsigned*)(ws + 19200000);             // 3,200,000
  float4* xpad = (float4*)(ws + 22400000);                // 3,200,000
  unsigned short* H = (unsigned short*)(ws + 25600000);   // 19,531,250 (dead before packedB)
  unsigned* packedB = (unsigned*)(ws + 25600000);         // 25,600,000 (CSR src indices)
  unsigned* t2h = (unsigned*)(ws + 51200000);             // 6,400,000
  unsigned* pooled = (unsigned*)(ws + 57600000);          // 16,384
  unsigned* bucketStart = (unsigned*)(ws + 57616384);     // 12,504 (NB+1)
  unsigned* bucketTotal = (unsigned*)(ws + 57628888);     // 12,500
  unsigned* P = (unsigned*)(ws + 57641388);               // 312,500
  unsigned* nodeStart = (unsigned*)(ws + 57953888);       // 800,004

  hipMemsetAsync(pooled, 0, N_GRAPHS * 8 * sizeof(unsigned), stream);

  // partition: two-level counting sort to full dst-CSR
  count_kernel<<<NCH, 256, 0, stream>>>(dst, H);
  scan_bins1_kernel<<<dim3((NB + 255) / 256, NGRP), 256, 0, stream>>>(H, P);
  scan_bins2_kernel<<<(NB + 255) / 256, 256, 0, stream>>>(P, bucketTotal);
  scan_total_kernel<<<1, 256, 0, stream>>>(bucketTotal, bucketStart);
  scatter_sorted_kernel<<<NCH, 256, 0, stream>>>(src, dst, H, P, bucketStart, packedA);
  sort2_kernel<<<NB, 256, 0, stream>>>(packedA, bucketStart, packedB, nodeStart);
  xpad_kernel<<<(N_NODES + 255) / 256, 256, 0, stream>>>(x, xpad);  // after sort2: aliases packedA

  // layers: atomic-free register accumulation over CSR runs, nt-protected L2
  layer1_kernel<<<NB, 256, 0, stream>>>(packedB, nodeStart, xpad,
                                        W1_rel, b1, W1_root, W2_rel, W2_root, t2h, r2);
  layer2_kernel<<<N_NODES / 32, 256, 0, stream>>>(packedB, nodeStart, (const uint4*)t2h, r2, b2,
                                                  W3_rel, W3_root, t3h, r3);
  layer3_kernel<<<N_NODES / 32, 256, 0, stream>>>(packedB, nodeStart, (const uint4*)t3h, r3, b3,
                                                  batch, pooled);
  final_kernel<<<(N_GRAPHS + 255) / 256, 256, 0, stream>>>(pooled, W_lin, b_lin, out);
}

// Round 8
// 506.182 us; speedup vs baseline: 7.8183x; 1.0989x over previous
//
#include <hip/hip_runtime.h>
#include <hip/hip_fp16.h>

#define N_NODES 200000
#define N_EDGES 6400000
#define N_GRAPHS 512

#define NB 3125      // 64-node dst buckets: 3125*64 = 200000 exactly
#define CHUNK 4096
#define NCH 1563     // 1563*4096 = 6,402,048 >= 6.4M (last chunk partial)
#define NGRP 25      // chunk groups for parallel scan
#define CPG 63       // chunks per group: 25*63 = 1575 >= 1563
#define SEG 13       // 256*13 = 3328 >= NB
#define SCAP 3072    // max edges per 64-node bucket (mean 2048)

// ---------- non-temporal helpers ----------
typedef float vf4 __attribute__((ext_vector_type(4)));
typedef float vf2 __attribute__((ext_vector_type(2)));
typedef unsigned vu2 __attribute__((ext_vector_type(2)));

__device__ __forceinline__ unsigned ntload_u(const unsigned* p) {
  return __builtin_nontemporal_load(p);
}
__device__ __forceinline__ int ntload_i(const int* p) { return __builtin_nontemporal_load(p); }
__device__ __forceinline__ float ntload_f(const float* p) {
  return __builtin_nontemporal_load(p);
}
__device__ __forceinline__ float2 ntload_f2(const float* p) {
  vf2 v = __builtin_nontemporal_load((const vf2*)p);
  return make_float2(v.x, v.y);
}
__device__ __forceinline__ void ntstore_u2(unsigned* p, uint2 v) {
  vu2 t = {v.x, v.y};
  __builtin_nontemporal_store(t, (vu2*)p);
}
__device__ __forceinline__ void ntstore_f2(float* p, float2 v) {
  vf2 t = {v.x, v.y};
  __builtin_nontemporal_store(t, (vf2*)p);
}
__device__ __forceinline__ void ntstore_f4(float* p, float4 v) {
  vf4 t = {v.x, v.y, v.z, v.w};
  __builtin_nontemporal_store(t, (vf4*)p);
}
__device__ __forceinline__ void ntstore_u(unsigned* p, unsigned v) {
  __builtin_nontemporal_store(v, p);
}

// ---------- partition pass 1: counting sort of edges by dst>>6 ----------
// H (ushort) TRANSPOSED: H[c*NB + b]

__global__ __launch_bounds__(256) void count_kernel(const int* __restrict__ dst,
                                                    unsigned short* __restrict__ H) {
  __shared__ unsigned hist[NB];
  for (int i = threadIdx.x; i < NB; i += 256) hist[i] = 0;
  __syncthreads();
  int c = blockIdx.x;
  long e0 = (long)c * CHUNK;
  long rem = (long)N_EDGES - e0;
  int n = rem > CHUNK ? CHUNK : (int)rem;
  for (int i = threadIdx.x; i < n; i += 256) atomicAdd(&hist[dst[e0 + i] >> 6], 1u);
  __syncthreads();
  for (int i = threadIdx.x; i < NB; i += 256) H[(size_t)c * NB + i] = (unsigned short)hist[i];
}

__global__ __launch_bounds__(256) void scan_bins1_kernel(unsigned short* __restrict__ H,
                                                         unsigned* __restrict__ P) {
  int b = blockIdx.x * 256 + threadIdx.x;
  int g = blockIdx.y;
  if (b >= NB) return;
  int c0 = g * CPG, c1 = min(NCH, (g + 1) * CPG);
  unsigned run = 0;
  for (int c = c0; c < c1; c++) {
    unsigned t = H[(size_t)c * NB + b];
    H[(size_t)c * NB + b] = (unsigned short)run;
    run += t;
  }
  P[(size_t)g * NB + b] = run;
}

__global__ __launch_bounds__(256) void scan_bins2_kernel(unsigned* __restrict__ P,
                                                         unsigned* __restrict__ bucketTotal) {
  int b = blockIdx.x * 256 + threadIdx.x;
  if (b >= NB) return;
  unsigned run = 0;
  for (int g = 0; g < NGRP; g++) {
    unsigned t = P[(size_t)g * NB + b];
    P[(size_t)g * NB + b] = run;
    run += t;
  }
  bucketTotal[b] = run;
}

// exclusive scan of totals -> bucketStart[NB+1] (one block)
__global__ __launch_bounds__(256) void scan_total_kernel(const unsigned* __restrict__ bucketTotal,
                                                         unsigned* __restrict__ bucketStart) {
  __shared__ unsigned sv[256 * SEG];
  __shared__ unsigned partial[256];
  int t = threadIdx.x;
  for (int i = t; i < 256 * SEG; i += 256) sv[i] = (i < NB) ? bucketTotal[i] : 0u;
  __syncthreads();
  unsigned sum = 0;
#pragma unroll
  for (int k = 0; k < SEG; k++) sum += sv[t * SEG + k];
  partial[t] = sum;
  __syncthreads();
  for (int off = 1; off < 256; off <<= 1) {
    unsigned add = (t >= off) ? partial[t - off] : 0u;
    __syncthreads();
    partial[t] += add;
    __syncthreads();
  }
  unsigned run = partial[t] - sum;
#pragma unroll
  for (int k = 0; k < SEG; k++) {
    unsigned w = sv[t * SEG + k];
    sv[t * SEG + k] = run;
    run += w;
  }
  __syncthreads();
  for (int i = t; i < NB; i += 256) bucketStart[i] = sv[i];
  if (t == 0) bucketStart[NB] = N_EDGES;
}

// chunk-local LDS counting sort by bucket, coalesced-run writes -> packedA = (src<<7)|dl
__global__ __launch_bounds__(256) void scatter_sorted_kernel(
    const int* __restrict__ src, const int* __restrict__ dst,
    const unsigned short* __restrict__ H, const unsigned* __restrict__ P,
    const unsigned* __restrict__ bucketStart, unsigned* __restrict__ packed) {
  __shared__ unsigned ssort[CHUNK];        // 16 KB
  __shared__ unsigned short sbort[CHUNK];  // 8 KB
  __shared__ unsigned hist[3328];          // 13.3 KB
  __shared__ unsigned cur[3328];           // 13.3 KB
  __shared__ unsigned partial[256];
  int t = threadIdx.x;
  int c = blockIdx.x;
  int g = c / CPG;
  long e0 = (long)c * CHUNK;
  long rem = (long)N_EDGES - e0;
  int n = rem > CHUNK ? CHUNK : (int)rem;
  for (int i = t; i < 3328; i += 256) hist[i] = 0;
  __syncthreads();
  for (int i = t; i < n; i += 256) atomicAdd(&hist[dst[e0 + i] >> 6], 1u);
  __syncthreads();
  unsigned a[SEG], sum = 0;
#pragma unroll
  for (int k = 0; k < SEG; k++) { a[k] = hist[SEG * t + k]; sum += a[k]; }
  partial[t] = sum;
  __syncthreads();
  for (int off = 1; off < 256; off <<= 1) {
    unsigned add = (t >= off) ? partial[t - off] : 0u;
    __syncthreads();
    partial[t] += add;
    __syncthreads();
  }
  unsigned run = partial[t] - sum;
#pragma unroll
  for (int k = 0; k < SEG; k++) {
    hist[SEG * t + k] = run;
    cur[SEG * t + k] = run;
    run += a[k];
  }
  __syncthreads();
  for (int i = t; i < n; i += 256) {
    int d = dst[e0 + i], s = src[e0 + i];
    int b = d >> 6;
    unsigned r = atomicAdd(&cur[b], 1u);
    ssort[r] = ((unsigned)s << 7) | (unsigned)(d & 63);
    sbort[r] = (unsigned short)b;
  }
  __syncthreads();
  for (int b = t; b < NB; b += 256)
    cur[b] = bucketStart[b] + P[(size_t)g * NB + b] + H[(size_t)c * NB + b] - hist[b];
  __syncthreads();
  for (int j = t; j < n; j += 256) packed[cur[sbort[j]] + j] = ssort[j];
}

// ---------- partition pass 2: within-bucket sort by node -> full CSR ----------
__global__ __launch_bounds__(256) void sort2_kernel(const unsigned* __restrict__ packedA,
                                                    const unsigned* __restrict__ bucketStart,
                                                    unsigned* __restrict__ packedB,
                                                    unsigned* __restrict__ nodeStart) {
  __shared__ unsigned buf[SCAP];
  __shared__ unsigned buf2[SCAP];
  __shared__ unsigned hist[64], base[64], cur[64];
  int t = threadIdx.x, b = blockIdx.x;
  unsigned s0 = bucketStart[b], s1 = bucketStart[b + 1];
  int n = (int)(s1 - s0);
  if (t < 64) hist[t] = 0;
  for (int i = t; i < n; i += 256) buf[i] = packedA[s0 + i];
  __syncthreads();
  for (int i = t; i < n; i += 256) atomicAdd(&hist[buf[i] & 63u], 1u);
  __syncthreads();
  if (t == 0) {
    unsigned run = 0;
    for (int k = 0; k < 64; k++) {
      unsigned v = hist[k];
      base[k] = run;
      cur[k] = run;
      run += v;
    }
  }
  __syncthreads();
  if (t < 64) nodeStart[b * 64 + t] = s0 + base[t];
  for (int i = t; i < n; i += 256) {
    unsigned p = buf[i];
    unsigned pos = atomicAdd(&cur[p & 63u], 1u);
    buf2[pos] = p >> 7;  // store src only; node implied by CSR position
  }
  __syncthreads();
  for (int i = t; i < n; i += 256) packedB[s0 + i] = buf2[i];
  if (b == NB - 1 && t == 0) nodeStart[N_NODES] = N_EDGES;
}

// ---------- xpad ----------
__global__ __launch_bounds__(256) void xpad_kernel(const float* __restrict__ x,
                                                   float4* __restrict__ xp) {
  int n = blockIdx.x * 256 + threadIdx.x;
  if (n >= N_NODES) return;
  xp[n] = make_float4(x[3 * n], x[3 * n + 1], x[3 * n + 2], 0.f);
}

__device__ __forceinline__ void half8_unpack(uint4 g, float* f) {
  const __half2* h2 = reinterpret_cast<const __half2*>(&g);
#pragma unroll
  for (int j = 0; j < 4; j++) {
    float2 fj = __half22float2(h2[j]);
    f[2 * j] = fj.x;
    f[2 * j + 1] = fj.y;
  }
}

// ---------- layer 1: 4 thr/node, batch-4 independent gathers ----------
__global__ __launch_bounds__(256) void layer1_kernel(
    const unsigned* __restrict__ packed, const unsigned* __restrict__ nodeStart,
    const float4* __restrict__ xp,
    const float* __restrict__ W1_rel, const float* __restrict__ b1,
    const float* __restrict__ W1_root,
    const float* __restrict__ W2_rel, const float* __restrict__ W2_root,
    unsigned* __restrict__ t2h, float* __restrict__ r2) {
  __shared__ float sW1rel[96], sW1root[96], sb1[32], sW2rel[512], sW2root[512];
  __shared__ float plds[256 * 4];
  for (int i = threadIdx.x; i < 96; i += 256) { sW1rel[i] = W1_rel[i]; sW1root[i] = W1_root[i]; }
  for (int i = threadIdx.x; i < 32; i += 256) sb1[i] = b1[i];
  for (int i = threadIdx.x; i < 512; i += 256) { sW2rel[i] = W2_rel[i]; sW2root[i] = W2_root[i]; }
  __syncthreads();
  int t = threadIdx.x, ln = t >> 2, part = t & 3;
  int node = blockIdx.x * 64 + ln;
  unsigned s1v = ntload_u(&nodeStart[node + 1]);
  float a0 = 0.f, a1 = 0.f, a2 = 0.f;
  for (unsigned base = ntload_u(&nodeStart[node]) + part; base < s1v; base += 16) {
    unsigned i1 = base + 4, i2 = base + 8, i3 = base + 12;
    unsigned e0 = ntload_u(&packed[base]);
    unsigned e1 = ntload_u(&packed[i1]);
    unsigned e2 = ntload_u(&packed[i2]);
    unsigned e3 = ntload_u(&packed[i3]);
    float4 g0 = xp[e0], g1 = xp[e1], g2 = xp[e2], g3 = xp[e3];
    float m1 = (i1 < s1v) ? 1.f : 0.f;
    float m2 = (i2 < s1v) ? 1.f : 0.f;
    float m3 = (i3 < s1v) ? 1.f : 0.f;
    a0 += g0.x + m1 * g1.x + m2 * g2.x + m3 * g3.x;
    a1 += g0.y + m1 * g1.y + m2 * g2.y + m3 * g3.y;
    a2 += g0.z + m1 * g1.z + m2 * g2.z + m3 * g3.z;
  }
  plds[t * 4] = a0; plds[t * 4 + 1] = a1; plds[t * 4 + 2] = a2;
  __syncthreads();
  int pb = ln * 16;
  float A0 = plds[pb] + plds[pb + 4] + plds[pb + 8] + plds[pb + 12];
  float A1 = plds[pb + 1] + plds[pb + 5] + plds[pb + 9] + plds[pb + 13];
  float A2 = plds[pb + 2] + plds[pb + 6] + plds[pb + 10] + plds[pb + 14];
  float4 xv = xp[node];
  float h[32];
#pragma unroll
  for (int k = 0; k < 32; k++) {
    float v = sW1rel[3 * k] * A0 + sW1rel[3 * k + 1] * A1 + sW1rel[3 * k + 2] * A2 +
              sW1root[3 * k] * xv.x + sW1root[3 * k + 1] * xv.y + sW1root[3 * k + 2] * xv.z +
              sb1[k];
    h[k] = fmaxf(v, 0.f);
  }
  int jb = part * 4;
  float tv[4], rv[4];
#pragma unroll
  for (int j = 0; j < 4; j++) {
    float acc = 0.f, accr = 0.f;
#pragma unroll
    for (int k = 0; k < 32; k++) {
      acc += sW2rel[32 * (jb + j) + k] * h[k];
      accr += sW2root[32 * (jb + j) + k] * h[k];
    }
    tv[j] = acc;
    rv[j] = accr;
  }
  __half2 p0 = __halves2half2(__float2half_rn(tv[0]), __float2half_rn(tv[1]));
  __half2 p1 = __halves2half2(__float2half_rn(tv[2]), __float2half_rn(tv[3]));
  ntstore_u2(&t2h[(size_t)node * 8 + part * 2], make_uint2(*(unsigned*)&p0, *(unsigned*)&p1));
  ntstore_f4(&r2[(size_t)node * 16 + jb], make_float4(rv[0], rv[1], rv[2], rv[3]));
}

// ---------- layer 2: 8 thr/node (pair x half), batch-4 independent gathers ----------
__global__ __launch_bounds__(256) void layer2_kernel(
    const unsigned* __restrict__ packed, const unsigned* __restrict__ nodeStart,
    const uint4* __restrict__ t2h4, const float* __restrict__ r2,
    const float* __restrict__ b2,
    const float* __restrict__ W3_rel, const float* __restrict__ W3_root,
    unsigned* __restrict__ t3h, float* __restrict__ r3) {
  __shared__ float sW3rel[128], sW3root[128], sb2[16];
  __shared__ float plds[256 * 9];  // stride 9: conflict-free combine
  __shared__ float hlds[32 * 16];
  for (int i = threadIdx.x; i < 128; i += 256) { sW3rel[i] = W3_rel[i]; sW3root[i] = W3_root[i]; }
  if (threadIdx.x < 16) sb2[threadIdx.x] = b2[threadIdx.x];
  __syncthreads();
  int t = threadIdx.x, ln = t >> 3, p = t & 7;
  int node = blockIdx.x * 32 + ln;
  int half = p & 1;  // which 16B of the 32B record
  unsigned s1v = ntload_u(&nodeStart[node + 1]);
  float acc[8];
#pragma unroll
  for (int j = 0; j < 8; j++) acc[j] = 0.f;
  for (unsigned base = ntload_u(&nodeStart[node]) + (p >> 1); base < s1v; base += 16) {
    unsigned i1 = base + 4, i2 = base + 8, i3 = base + 12;
    unsigned e0 = ntload_u(&packed[base]);
    unsigned e1 = ntload_u(&packed[i1]);
    unsigned e2 = ntload_u(&packed[i2]);
    unsigned e3 = ntload_u(&packed[i3]);
    uint4 g0 = t2h4[(size_t)e0 * 2 + half];
    uint4 g1 = t2h4[(size_t)e1 * 2 + half];
    uint4 g2 = t2h4[(size_t)e2 * 2 + half];
    uint4 g3 = t2h4[(size_t)e3 * 2 + half];
    float m1 = (i1 < s1v) ? 1.f : 0.f;
    float m2 = (i2 < s1v) ? 1.f : 0.f;
    float m3 = (i3 < s1v) ? 1.f : 0.f;
    float f0[8], f1[8], f2[8], f3[8];
    half8_unpack(g0, f0);
    half8_unpack(g1, f1);
    half8_unpack(g2, f2);
    half8_unpack(g3, f3);
#pragma unroll
    for (int j = 0; j < 8; j++)
      acc[j] += f0[j] + m1 * f1[j] + m2 * f2[j] + m3 * f3[j];
  }
#pragma unroll
  for (int j = 0; j < 8; j++) plds[t * 9 + j] = acc[j];
  __syncthreads();
  // h: thread computes feats 2p, 2p+1
  {
    float2 rv = ntload_f2(&r2[(size_t)node * 16 + 2 * p]);
    float hv[2];
#pragma unroll
    for (int k2 = 0; k2 < 2; k2++) {
      int f = 2 * p + k2;
      int fh = f >> 3, fi = f & 7;
      int q0 = (ln * 8 + fh) * 9 + fi;
      float s = plds[q0] + plds[q0 + 18] + plds[q0 + 36] + plds[q0 + 54];
      hv[k2] = s + sb2[f] + (k2 == 0 ? rv.x : rv.y);
    }
    hlds[ln * 16 + 2 * p] = fmaxf(hv[0], 0.f);
    hlds[ln * 16 + 2 * p + 1] = fmaxf(hv[1], 0.f);
  }
  __syncthreads();
  // rows: p<4 -> W3_rel rows 2p,2p+1 (t3); p>=4 -> W3_root rows 2(p-4).. (r3)
  const float* W = (p < 4) ? sW3rel : sW3root;
  int rbase = (p < 4) ? 2 * p : 2 * (p - 4);
  float o0 = 0.f, o1 = 0.f;
#pragma unroll
  for (int k = 0; k < 16; k++) {
    float hv = hlds[ln * 16 + k];
    o0 += W[16 * rbase + k] * hv;
    o1 += W[16 * (rbase + 1) + k] * hv;
  }
  if (p < 4) {
    __half2 pk = __halves2half2(__float2half_rn(o0), __float2half_rn(o1));
    ntstore_u(&t3h[(size_t)node * 4 + p], *(unsigned*)&pk);
  } else {
    ntstore_f2(&r3[(size_t)node * 8 + rbase], make_float2(o0, o1));
  }
}

// ---------- layer 3: 8 thr/node, batch-4 independent gathers, fused relu + pool ----------
__global__ __launch_bounds__(256) void layer3_kernel(
    const unsigned* __restrict__ packed, const unsigned* __restrict__ nodeStart,
    const uint4* __restrict__ t3h4, const float* __restrict__ r3,
    const float* __restrict__ b3,
    const int* __restrict__ batch, unsigned* __restrict__ pooled) {
  __shared__ float plds[256 * 9];
  __shared__ float sb3[8];
  if (threadIdx.x < 8) sb3[threadIdx.x] = b3[threadIdx.x];
  __syncthreads();
  int t = threadIdx.x, ln = t >> 3, p = t & 7;
  int node = blockIdx.x * 32 + ln;
  unsigned s1v = ntload_u(&nodeStart[node + 1]);
  float acc[8];
#pragma unroll
  for (int j = 0; j < 8; j++) acc[j] = 0.f;
  for (unsigned base = ntload_u(&nodeStart[node]) + p; base < s1v; base += 32) {
    unsigned i1 = base + 8, i2 = base + 16, i3 = base + 24;
    unsigned e0 = ntload_u(&packed[base]);
    unsigned e1 = ntload_u(&packed[i1]);
    unsigned e2 = ntload_u(&packed[i2]);
    unsigned e3 = ntload_u(&packed[i3]);
    uint4 g0 = t3h4[e0];
    uint4 g1 = t3h4[e1];
    uint4 g2 = t3h4[e2];
    uint4 g3 = t3h4[e3];
    float m1 = (i1 < s1v) ? 1.f : 0.f;
    float m2 = (i2 < s1v) ? 1.f : 0.f;
    float m3 = (i3 < s1v) ? 1.f : 0.f;
    float f0[8], f1[8], f2[8], f3[8];
    half8_unpack(g0, f0);
    half8_unpack(g1, f1);
    half8_unpack(g2, f2);
    half8_unpack(g3, f3);
#pragma unroll
    for (int j = 0; j < 8; j++)
      acc[j] += f0[j] + m1 * f1[j] + m2 * f2[j] + m3 * f3[j];
  }
#pragma unroll
  for (int j = 0; j < 8; j++) plds[t * 9 + j] = acc[j];
  __syncthreads();
  int gg = ntload_i(&batch[node]);
  int q0 = ln * 72 + p;  // (ln*8+k)*9 + p, k=0..7
  float v = plds[q0] + plds[q0 + 9] + plds[q0 + 18] + plds[q0 + 27] +
            plds[q0 + 36] + plds[q0 + 45] + plds[q0 + 54] + plds[q0 + 63];
  float h = fmaxf(v + sb3[p] + ntload_f(&r3[(size_t)node * 8 + p]), 0.f);
  atomicMax(&pooled[8 * gg + p], __float_as_uint(h));  // relu>=0: uint order==float order
}

__global__ __launch_bounds__(256) void final_kernel(
    const unsigned* __restrict__ pooled, const float* __restrict__ W_lin,
    const float* __restrict__ b_lin, float* __restrict__ out) {
  int g = blockIdx.x * blockDim.x + threadIdx.x;
  if (g >= N_GRAPHS) return;
  float acc = b_lin[0];
#pragma unroll
  for (int f = 0; f < 8; f++) acc += __uint_as_float(pooled[8 * g + f]) * W_lin[f];
  out[g] = acc;
}

extern "C" void kernel_launch(void* const* d_in, const int* in_sizes, int n_in,
                              void* d_out, int out_size, void* d_ws, size_t ws_size,
                              hipStream_t stream) {
  const float* x = (const float*)d_in[0];
  const int* ei = (const int*)d_in[1];
  const int* src = ei;
  const int* dst = ei + N_EDGES;
  const int* batch = (const int*)d_in[2];
  const float* W1_rel = (const float*)d_in[3];
  const float* b1 = (const float*)d_in[4];
  const float* W1_root = (const float*)d_in[5];
  const float* W2_rel = (const float*)d_in[6];
  const float* b2 = (const float*)d_in[7];
  const float* W2_root = (const float*)d_in[8];
  const float* W3_rel = (const float*)d_in[9];
  const float* b3 = (const float*)d_in[10];
  const float* W3_root = (const float*)d_in[11];
  const float* W_lin = (const float*)d_in[12];
  const float* b_lin = (const float*)d_in[13];
  float* out = (float*)d_out;

  // ---- workspace layout (bytes) ----
  // region0 [0, 25.6M): packedA (partition); post-sort2: r2|r3|t3h|xpad
  // region1 [25.6M, 51.2M+128): H (9.77M, dead) then packedB (25.6M) + 128B zero pad
  char* ws = (char*)d_ws;
  unsigned* packedA = (unsigned*)(ws + 0);                // 25,600,000
  float* r2 = (float*)(ws + 0);                           // 12,800,000 (alias, post-sort2)
  float* r3 = (float*)(ws + 12800000);                    // 6,400,000
  unsigned* t3h = (unsigned*)(ws + 19200000);             // 3,200,000
  float4* xpad = (float4*)(ws + 22400000);                // 3,200,000
  unsigned short* H = (unsigned short*)(ws + 25600000);   // 9,768,750 (dead before packedB)
  unsigned* packedB = (unsigned*)(ws + 25600000);         // 25,600,000 + 128 pad
  unsigned* t2h = (unsigned*)(ws + 51200128);             // 6,400,000
  unsigned* pooled = (unsigned*)(ws + 57600128);          // 16,384
  unsigned* bucketStart = (unsigned*)(ws + 57616512);     // 12,504 (NB+1)
  unsigned* bucketTotal = (unsigned*)(ws + 57629016);     // 12,500
  unsigned* P = (unsigned*)(ws + 57641516);               // 312,500
  unsigned* nodeStart = (unsigned*)(ws + 57954016);       // 800,004 -> end 58,754,020

  hipMemsetAsync(pooled, 0, N_GRAPHS * 8 * sizeof(unsigned), stream);
  hipMemsetAsync(packedB + N_EDGES, 0, 128, stream);  // batch-4 overrun pad (src=0 safe)

  // partition: two-level counting sort to full dst-CSR
  count_kernel<<<NCH, 256, 0, stream>>>(dst, H);
  scan_bins1_kernel<<<dim3((NB + 255) / 256, NGRP), 256, 0, stream>>>(H, P);
  scan_bins2_kernel<<<(NB + 255) / 256, 256, 0, stream>>>(P, bucketTotal);
  scan_total_kernel<<<1, 256, 0, stream>>>(bucketTotal, bucketStart);
  scatter_sorted_kernel<<<NCH, 256, 0, stream>>>(src, dst, H, P, bucketStart, packedA);
  sort2_kernel<<<NB, 256, 0, stream>>>(packedA, bucketStart, packedB, nodeStart);
  xpad_kernel<<<(N_NODES + 255) / 256, 256, 0, stream>>>(x, xpad);  // after sort2 (aliases packedA)

  // layers: atomic-free register accumulation, batch-4 independent gathers
  layer1_kernel<<<NB, 256, 0, stream>>>(packedB, nodeStart, xpad,
                                        W1_rel, b1, W1_root, W2_rel, W2_root, t2h, r2);
  layer2_kernel<<<N_NODES / 32, 256, 0, stream>>>(packedB, nodeStart, (const uint4*)t2h, r2, b2,
                                                  W3_rel, W3_root, t3h, r3);
  layer3_kernel<<<N_NODES / 32, 256, 0, stream>>>(packedB, nodeStart, (const uint4*)t3h, r3, b3,
                                                  batch, pooled);
  final_kernel<<<(N_GRAPHS + 255) / 256, 256, 0, stream>>>(pooled, W_lin, b_lin, out);
}